// Round 16
// baseline (329.339 us; speedup 1.0000x reference)
//
#include <hip/hip_runtime.h>
#include <hip/hip_bf16.h>

#define BB 2
#define TT 4096
#define DD 128
#define KK 256
#define NROW (BB*TT)    // 8192 rows
#define NELT (NROW*DD)  // 1048576 elements per [B,T,D] buffer

typedef _Float16 f16;
typedef __attribute__((ext_vector_type(8))) f16 half8;
typedef __attribute__((ext_vector_type(2))) __fp16 fp16x2;
typedef __attribute__((ext_vector_type(4))) float f32x4;
typedef __attribute__((ext_vector_type(2))) int i32x2;

__device__ __forceinline__ int pack2(float a, float b){
  fp16x2 h = __builtin_amdgcn_cvt_pkrtz(a, b);
  return __builtin_bit_cast(int, h);
}

// ================= k_proj: k_hat = normalize(z@Wk+bk) -> fp16 [T][D] and [D][T] =================
__global__ __launch_bounds__(256) void k_proj(
    const float* __restrict__ z, const float* __restrict__ Wk, const float* __restrict__ bk,
    f16* __restrict__ khb, f16* __restrict__ khT)
{
  __shared__ float Ws[DD*DD];
  __shared__ float zs[32*DD];
  int tid = threadIdx.x;
  int r0 = blockIdx.x * 32;
  #pragma unroll
  for (int it = 0; it < 16; it++){
    int idx = tid + it*256;
    *(f32x4*)(Ws + idx*4) = *(const f32x4*)(Wk + (size_t)idx*4);
  }
  #pragma unroll
  for (int it = 0; it < 4; it++){
    int idx = tid + it*256;
    *(f32x4*)(zs + idx*4) = *(const f32x4*)(z + (size_t)r0*DD + idx*4);
  }
  __syncthreads();
  int c = tid & 15, rr = tid >> 4;
  float acc0[8], acc1[8];
  #pragma unroll
  for (int u = 0; u < 8; u++){ float bv = bk[c*8+u]; acc0[u] = bv; acc1[u] = bv; }
  const float* zr0 = zs + rr*DD;
  const float* zr1 = zs + (rr+16)*DD;
  #pragma unroll 4
  for (int i = 0; i < DD; i++){
    f32x4 w0 = *(const f32x4*)(Ws + i*DD + c*8);
    f32x4 w1 = *(const f32x4*)(Ws + i*DD + c*8 + 4);
    float a0 = zr0[i], a1 = zr1[i];
    #pragma unroll
    for (int u = 0; u < 4; u++){
      acc0[u]   = fmaf(a0, w0[u], acc0[u]);   acc1[u]   = fmaf(a1, w0[u], acc1[u]);
      acc0[4+u] = fmaf(a0, w1[u], acc0[4+u]); acc1[4+u] = fmaf(a1, w1[u], acc1[4+u]);
    }
  }
  float s0 = 0.f, s1 = 0.f;
  #pragma unroll
  for (int u = 0; u < 8; u++){ s0 = fmaf(acc0[u], acc0[u], s0); s1 = fmaf(acc1[u], acc1[u], s1); }
  #pragma unroll
  for (int m = 1; m < 16; m <<= 1){ s0 += __shfl_xor(s0, m, 16); s1 += __shfl_xor(s1, m, 16); }
  float inv0 = 1.f / fmaxf(sqrtf(s0), 1e-8f);
  float inv1 = 1.f / fmaxf(sqrtf(s1), 1e-8f);
  half8 h0, h1;
  #pragma unroll
  for (int u = 0; u < 8; u++){ h0[u] = (f16)(acc0[u]*inv0); h1[u] = (f16)(acc1[u]*inv1); }
  int row0 = r0 + rr, row1 = row0 + 16;
  *(half8*)(khb + (size_t)row0*DD + c*8) = h0;
  *(half8*)(khb + (size_t)row1*DD + c*8) = h1;
  int b = row0 >> 12, t0 = row0 & 4095, t1 = row1 & 4095;
  #pragma unroll
  for (int u = 0; u < 8; u++){
    khT[((size_t)b*DD + c*8 + u)*TT + t0] = h0[u];
    khT[((size_t)b*DD + c*8 + u)*TT + t1] = h1[u];
  }
}

// ================= k_conv: causal depthwise conv, register sliding window =================
__global__ __launch_bounds__(256) void k_conv(
    const float* __restrict__ z, const float* __restrict__ ck, const float* __restrict__ cb,
    float* __restrict__ mf)
{
  int tid = threadIdx.x;
  int d = tid & 127, tg = tid >> 7;
  int bid = blockIdx.x;
  int b = bid >> 8;
  int tbase = ((bid & 255) << 4) + tg*8;
  const float* zb = z + (size_t)b*TT*DD;
  float acc[8];
  #pragma unroll
  for (int j = 0; j < 8; j++) acc[j] = 0.f;
  float ckq[8];
  #pragma unroll
  for (int u = 0; u < 8; u++) ckq[u] = 0.f;
  int sstart = tbase - (KK-1);
  for (int ch = 0; ch < 33; ch++){
    #pragma unroll
    for (int u = 0; u < 8; u++){
      int base = ch*8 + u;
      int s = sstart + base;
      float zv = ((unsigned)s < (unsigned)TT && base < 263) ? zb[(size_t)s*DD + d] : 0.f;
      ckq[u] = (base < KK) ? ck[(size_t)base*DD + d] : 0.f;
      #pragma unroll
      for (int j = 0; j < 8; j++) acc[j] = fmaf(ckq[(u-j)&7], zv, acc[j]);
    }
  }
  float cbv = cb[d];
  #pragma unroll
  for (int j = 0; j < 8; j++)
    mf[((size_t)b*TT + tbase + j)*DD + d] = acc[j] + cbv;
}

// ================= k_q: q_hat = normalize(zcur@Wq+bq) -> fp16 =================
__global__ __launch_bounds__(256) void k_q(
    const float* __restrict__ zcur, const float* __restrict__ Wq, const float* __restrict__ bq,
    f16* __restrict__ qhb)
{
  __shared__ float Ws[DD*DD];
  __shared__ float zs[32*DD];
  int tid = threadIdx.x;
  int r0 = blockIdx.x * 32;
  #pragma unroll
  for (int it = 0; it < 16; it++){
    int idx = tid + it*256;
    *(f32x4*)(Ws + idx*4) = *(const f32x4*)(Wq + (size_t)idx*4);
  }
  #pragma unroll
  for (int it = 0; it < 4; it++){
    int idx = tid + it*256;
    *(f32x4*)(zs + idx*4) = *(const f32x4*)(zcur + (size_t)r0*DD + idx*4);
  }
  __syncthreads();
  int c = tid & 15, rr = tid >> 4;
  float acc0[8], acc1[8];
  #pragma unroll
  for (int u = 0; u < 8; u++){ float bv = bq[c*8+u]; acc0[u] = bv; acc1[u] = bv; }
  const float* zr0 = zs + rr*DD;
  const float* zr1 = zs + (rr+16)*DD;
  #pragma unroll 4
  for (int i = 0; i < DD; i++){
    f32x4 w0 = *(const f32x4*)(Ws + i*DD + c*8);
    f32x4 w1 = *(const f32x4*)(Ws + i*DD + c*8 + 4);
    float a0 = zr0[i], a1 = zr1[i];
    #pragma unroll
    for (int u = 0; u < 4; u++){
      acc0[u]   = fmaf(a0, w0[u], acc0[u]);   acc1[u]   = fmaf(a1, w0[u], acc1[u]);
      acc0[4+u] = fmaf(a0, w1[u], acc0[4+u]); acc1[4+u] = fmaf(a1, w1[u], acc1[4+u]);
    }
  }
  float s0 = 0.f, s1 = 0.f;
  #pragma unroll
  for (int u = 0; u < 8; u++){ s0 = fmaf(acc0[u], acc0[u], s0); s1 = fmaf(acc1[u], acc1[u], s1); }
  #pragma unroll
  for (int m = 1; m < 16; m <<= 1){ s0 += __shfl_xor(s0, m, 16); s1 += __shfl_xor(s1, m, 16); }
  float inv0 = 1.f / fmaxf(sqrtf(s0), 1e-8f);
  float inv1 = 1.f / fmaxf(sqrtf(s1), 1e-8f);
  half8 h0, h1;
  #pragma unroll
  for (int u = 0; u < 8; u++){ h0[u] = (f16)(acc0[u]*inv0); h1[u] = (f16)(acc1[u]*inv1); }
  *(half8*)(qhb + (size_t)(r0+rr)*DD + c*8) = h0;
  *(half8*)(qhb + (size_t)(r0+rr+16)*DD + c*8) = h1;
}

// ====== MFMA attention v11: R13 core, chunks of 2 key-tiles (1056 blocks, <=2 iters/block) =====
#define QTILE 128
#define NQT3 (TT/QTILE)     // 32 q-tiles per batch
#define NCHUNK 528          // sum_{qt=0}^{31} (qt+1)

__global__ __launch_bounds__(256,2) void k_attn11(
    const f16* __restrict__ qhb, const f16* __restrict__ khb,
    const f16* __restrict__ khT, f16* __restrict__ part)
{
  int bid = blockIdx.x;
  int b = bid / NCHUNK;
  int rem = bid - b*NCHUNK;
  int qt = 0, chunk = 0;
  #pragma unroll 1
  for (int j = 0; j < NQT3; j++){
    int nch = j + 1;            // chunks of 2 key-tiles; key tiles = 2qt+2
    if (rem < nch){ qt = j; chunk = rem; break; }
    rem -= nch;
  }
  int kt0 = chunk * 2;
  int kt1 = min(kt0 + 1, 2*qt + 1);
  int t0 = qt * QTILE;

  __shared__ __align__(16) f16 Kb[64*136];     // [key][dim],  stride 136 (17408 B)
  __shared__ __align__(16) f16 Kt[128*72];     // [dim][key],  stride 72  (18432 B)
  __shared__ __align__(16) f16 Ps[4][32*72];   // per-wave P fp16, [q][key], stride 72 (18432 B)

  int tid  = threadIdx.x;
  int w    = tid >> 6;
  int lane = tid & 63;
  int n16  = lane & 15;
  int g    = lane >> 4;

  const f16* qg  = qhb + (size_t)b*TT*DD;
  const f16* kg  = khb + (size_t)b*TT*DD;
  const f16* ktg = khT + (size_t)b*DD*TT;

  int sb_r  = tid >> 4, sb_c = (tid & 15)*8;   // Kb staging base
  int st_r  = tid >> 3, st_c = (tid & 7)*8;    // Kt staging base

  half8 qa[2][4];   // Q rows; used as MFMA B-operand (A/B lane maps identical for 16x16x32 f16)
  #pragma unroll
  for (int p = 0; p < 2; p++){
    const f16* qrow = qg + (size_t)(t0 + 32*w + 16*p + n16)*DD + g*8;
    #pragma unroll
    for (int c = 0; c < 4; c++) qa[p][c] = *(const half8*)(qrow + 32*c);
  }
  f32x4 acc[2][8];
  #pragma unroll
  for (int p = 0; p < 2; p++)
    #pragma unroll
    for (int i = 0; i < 8; i++) acc[p][i] = (f32x4){0.f,0.f,0.f,0.f};

  f16* psw = &Ps[w][0];

  // ---- register prefetch of first K tile ----
  half8 sKb[4], sKt[4];
  {
    int s0 = kt0 * 64;
    #pragma unroll
    for (int it = 0; it < 4; it++)
      sKb[it] = *(const half8*)(kg + (size_t)(s0 + sb_r + it*16)*DD + sb_c);
    #pragma unroll
    for (int it = 0; it < 4; it++)
      sKt[it] = *(const half8*)(ktg + (size_t)(st_r + it*32)*TT + s0 + st_c);
  }

  for (int kt = kt0; kt <= kt1; kt++){
    #pragma unroll
    for (int it = 0; it < 4; it++)
      *(half8*)(Kb + (sb_r + it*16)*136 + sb_c) = sKb[it];
    #pragma unroll
    for (int it = 0; it < 4; it++)
      *(half8*)(Kt + (st_r + it*32)*72 + st_c) = sKt[it];
    __syncthreads();

    if (kt < kt1){
      int s0n = (kt+1) * 64;
      #pragma unroll
      for (int it = 0; it < 4; it++)
        sKb[it] = *(const half8*)(kg + (size_t)(s0n + sb_r + it*16)*DD + sb_c);
      #pragma unroll
      for (int it = 0; it < 4; it++)
        sKt[it] = *(const half8*)(ktg + (size_t)(st_r + it*32)*TT + s0n + st_c);
    }

    int s0 = kt * 64;
    // ---- QK^T transposed: A = K rows (Kb), B = Q regs -> S^T[m=key][n=query] ----
    f32x4 s_acc[2][4];
    #pragma unroll
    for (int p = 0; p < 2; p++)
      #pragma unroll
      for (int n = 0; n < 4; n++) s_acc[p][n] = (f32x4){0.f,0.f,0.f,0.f};
    #pragma unroll
    for (int c = 0; c < 4; c++){
      #pragma unroll
      for (int n = 0; n < 4; n++){
        half8 af = *(const half8*)(Kb + (16*n + n16)*136 + 32*c + g*8);
        s_acc[0][n] = __builtin_amdgcn_mfma_f32_16x16x32_f16(af, qa[0][c], s_acc[0][n], 0,0,0);
        s_acc[1][n] = __builtin_amdgcn_mfma_f32_16x16x32_f16(af, qa[1][c], s_acc[1][n], 0,0,0);
      }
    }
    // ---- sin + mask; lane holds q=n16, keys 16n+4g+r -> pack 4 keys -> ONE b64 write ----
    #pragma unroll
    for (int p = 0; p < 2; p++){
      int qrow = t0 + 32*w + 16*p + n16;
      #pragma unroll
      for (int n = 0; n < 4; n++){
        int keyr = s0 + 16*n + 4*g;
        float v0 = (keyr     <= qrow) ? __sinf(s_acc[p][n][0]) : 0.f;
        float v1 = (keyr + 1 <= qrow) ? __sinf(s_acc[p][n][1]) : 0.f;
        float v2 = (keyr + 2 <= qrow) ? __sinf(s_acc[p][n][2]) : 0.f;
        float v3 = (keyr + 3 <= qrow) ? __sinf(s_acc[p][n][3]) : 0.f;
        i32x2 pw = { pack2(v0, v1), pack2(v2, v3) };
        *(i32x2*)(psw + (16*p + n16)*72 + 16*n + 4*g) = pw;
      }
    }
    // intra-wave RAW on psw ordered by lgkmcnt (per-wave buffer, no barrier)

    // ---- PV: A = P rows (Ps[q][key] b128), B = Kt rows -> O[q][dim] ----
    #pragma unroll
    for (int h = 0; h < 2; h++){
      half8 pa[2];
      #pragma unroll
      for (int p = 0; p < 2; p++)
        pa[p] = *(const half8*)(psw + (16*p + n16)*72 + 32*h + 8*g);
      #pragma unroll
      for (int nt = 0; nt < 8; nt++){
        half8 bf = *(const half8*)(Kt + (16*nt + n16)*72 + 32*h + 8*g);
        acc[0][nt] = __builtin_amdgcn_mfma_f32_16x16x32_f16(pa[0], bf, acc[0][nt], 0,0,0);
        acc[1][nt] = __builtin_amdgcn_mfma_f32_16x16x32_f16(pa[1], bf, acc[1][nt], 0,0,0);
      }
    }
    __syncthreads();   // protect Kb/Kt/psw before next staging
  }

  // ---- epilogue: fp16 partial store ([q][dim] contiguous per chunk) ----
  f16* pb = part + (size_t)bid*(QTILE*DD) + (32*w)*DD;
  #pragma unroll
  for (int p = 0; p < 2; p++){
    #pragma unroll
    for (int nt = 0; nt < 8; nt++){
      #pragma unroll
      for (int r = 0; r < 4; r++){
        pb[(size_t)(16*p + 4*g + r)*DD + 16*nt + n16] = (f16)acc[p][nt][r];
      }
    }
  }
}

// ================= k_reduce: att[b,qtile rows,:] = sum of fp16 partials (f32 accum) ===========
__global__ __launch_bounds__(256) void k_reduce(
    const f16* __restrict__ part, float* __restrict__ att)
{
  int bid = blockIdx.x;            // BB * 32 * 8 blocks
  int rg = bid & 7;
  int qt = (bid >> 3) & 31;
  int b  = bid >> 8;
  int nc = qt + 1;                 // chunks of 2 key-tiles
  int base = (qt*(qt+1)) >> 1;     // prefix sum_{j<qt}(j+1)
  int tid = threadIdx.x;
  size_t off = (size_t)rg*(16*DD) + tid*8;
  const f16* src = part + ((size_t)b*NCHUNK + base)*(QTILE*DD) + off;
  float a[8];
  {
    half8 v = *(const half8*)(src);
    #pragma unroll
    for (int u = 0; u < 8; u++) a[u] = (float)v[u];
  }
  for (int c = 1; c < nc; c++){
    half8 v = *(const half8*)(src + (size_t)c*(QTILE*DD));
    #pragma unroll
    for (int u = 0; u < 8; u++) a[u] += (float)v[u];
  }
  float* dst = att + ((size_t)b*TT + (size_t)qt*QTILE)*DD + off;
  f32x4 o0 = {a[0],a[1],a[2],a[3]}, o1 = {a[4],a[5],a[6],a[7]};
  *(f32x4*)(dst) = o0;
  *(f32x4*)(dst + 4) = o1;
}

// ================= k_comb: ki = proj(mf + att@Wo + bo); vsum += w*ki; retract =================
__global__ __launch_bounds__(256) void k_comb(
    const float* __restrict__ z, const float* __restrict__ Wo, const float* __restrict__ bo,
    const float* __restrict__ mf, const float* __restrict__ att,
    const float* __restrict__ zin, float* __restrict__ zout,
    float* __restrict__ vsum, float* __restrict__ out,
    float wsum, float cretr, int first, int last)
{
  __shared__ float Ws[DD*DD];
  __shared__ float As[32*DD];
  int tid = threadIdx.x;
  int r0 = blockIdx.x * 32;
  #pragma unroll
  for (int it = 0; it < 16; it++){
    int idx = tid + it*256;
    *(f32x4*)(Ws + idx*4) = *(const f32x4*)(Wo + (size_t)idx*4);
  }
  #pragma unroll
  for (int it = 0; it < 4; it++){
    int idx = tid + it*256;
    *(f32x4*)(As + idx*4) = *(const f32x4*)(att + (size_t)r0*DD + idx*4);
  }
  __syncthreads();
  int c = tid & 15, rr = tid >> 4;
  float kur0[8], kur1[8];
  #pragma unroll
  for (int u = 0; u < 8; u++){ float bv = bo[c*8+u]; kur0[u] = bv; kur1[u] = bv; }
  const float* ar0 = As + rr*DD;
  const float* ar1 = As + (rr+16)*DD;
  #pragma unroll 4
  for (int i = 0; i < DD; i++){
    f32x4 w0 = *(const f32x4*)(Ws + i*DD + c*8);
    f32x4 w1 = *(const f32x4*)(Ws + i*DD + c*8 + 4);
    float a0 = ar0[i], a1 = ar1[i];
    #pragma unroll
    for (int u = 0; u < 4; u++){
      kur0[u]   = fmaf(a0, w0[u], kur0[u]);   kur1[u]   = fmaf(a1, w0[u], kur1[u]);
      kur0[4+u] = fmaf(a0, w1[u], kur0[4+u]); kur1[4+u] = fmaf(a1, w1[u], kur1[4+u]);
    }
  }
  size_t o0 = (size_t)(r0+rr)*DD + c*8;
  size_t o1 = (size_t)(r0+rr+16)*DD + c*8;
  float tot0[8], tot1[8], zi0[8], zi1[8];
  {
    f32x4 m0a = *(const f32x4*)(mf + o0), m0b = *(const f32x4*)(mf + o0 + 4);
    f32x4 m1a = *(const f32x4*)(mf + o1), m1b = *(const f32x4*)(mf + o1 + 4);
    f32x4 z0a = *(const f32x4*)(zin + o0), z0b = *(const f32x4*)(zin + o0 + 4);
    f32x4 z1a = *(const f32x4*)(zin + o1), z1b = *(const f32x4*)(zin + o1 + 4);
    #pragma unroll
    for (int u = 0; u < 4; u++){
      tot0[u] = m0a[u] + kur0[u]; tot0[4+u] = m0b[u] + kur0[4+u];
      tot1[u] = m1a[u] + kur1[u]; tot1[4+u] = m1b[u] + kur1[4+u];
      zi0[u] = z0a[u]; zi0[4+u] = z0b[u];
      zi1[u] = z1a[u]; zi1[4+u] = z1b[u];
    }
  }
  float p0 = 0.f, p1 = 0.f;
  #pragma unroll
  for (int u = 0; u < 8; u++){ p0 = fmaf(tot0[u], zi0[u], p0); p1 = fmaf(tot1[u], zi1[u], p1); }
  #pragma unroll
  for (int m = 1; m < 16; m <<= 1){ p0 += __shfl_xor(p0, m, 16); p1 += __shfl_xor(p1, m, 16); }
  float ki0[8], ki1[8], vs0[8], vs1[8];
  #pragma unroll
  for (int u = 0; u < 8; u++){
    ki0[u] = tot0[u] - p0 * zi0[u];
    ki1[u] = tot1[u] - p1 * zi1[u];
  }
  if (first){
    #pragma unroll
    for (int u = 0; u < 8; u++){ vs0[u] = wsum*ki0[u]; vs1[u] = wsum*ki1[u]; }
  } else {
    f32x4 v0a = *(const f32x4*)(vsum + o0), v0b = *(const f32x4*)(vsum + o0 + 4);
    f32x4 v1a = *(const f32x4*)(vsum + o1), v1b = *(const f32x4*)(vsum + o1 + 4);
    #pragma unroll
    for (int u = 0; u < 4; u++){
      vs0[u] = fmaf(wsum, ki0[u], v0a[u]); vs0[4+u] = fmaf(wsum, ki0[4+u], v0b[u]);
      vs1[u] = fmaf(wsum, ki1[u], v1a[u]); vs1[4+u] = fmaf(wsum, ki1[4+u], v1b[u]);
    }
  }
  if (!last){
    f32x4 va = {vs0[0],vs0[1],vs0[2],vs0[3]}, vb = {vs0[4],vs0[5],vs0[6],vs0[7]};
    f32x4 vc = {vs1[0],vs1[1],vs1[2],vs1[3]}, vd = {vs1[4],vs1[5],vs1[6],vs1[7]};
    *(f32x4*)(vsum + o0) = va; *(f32x4*)(vsum + o0 + 4) = vb;
    *(f32x4*)(vsum + o1) = vc; *(f32x4*)(vsum + o1 + 4) = vd;
  }
  float nz0[8], nz1[8];
  {
    f32x4 z0a = *(const f32x4*)(z + o0), z0b = *(const f32x4*)(z + o0 + 4);
    f32x4 z1a = *(const f32x4*)(z + o1), z1b = *(const f32x4*)(z + o1 + 4);
    #pragma unroll
    for (int u = 0; u < 4; u++){
      float d0a = last ? vs0[u]*(1.f/6.f)   : cretr*ki0[u];
      float d0b = last ? vs0[4+u]*(1.f/6.f) : cretr*ki0[4+u];
      float d1a = last ? vs1[u]*(1.f/6.f)   : cretr*ki1[u];
      float d1b = last ? vs1[4+u]*(1.f/6.f) : cretr*ki1[4+u];
      nz0[u] = z0a[u] + d0a; nz0[4+u] = z0b[u] + d0b;
      nz1[u] = z1a[u] + d1a; nz1[4+u] = z1b[u] + d1b;
    }
  }
  float n0 = 0.f, n1 = 0.f;
  #pragma unroll
  for (int u = 0; u < 8; u++){ n0 = fmaf(nz0[u], nz0[u], n0); n1 = fmaf(nz1[u], nz1[u], n1); }
  #pragma unroll
  for (int m = 1; m < 16; m <<= 1){ n0 += __shfl_xor(n0, m, 16); n1 += __shfl_xor(n1, m, 16); }
  float i0 = 1.f / fmaxf(sqrtf(n0), 1e-8f);
  float i1 = 1.f / fmaxf(sqrtf(n1), 1e-8f);
  float* dst = last ? out : zout;
  f32x4 ra = {nz0[0]*i0, nz0[1]*i0, nz0[2]*i0, nz0[3]*i0};
  f32x4 rb = {nz0[4]*i0, nz0[5]*i0, nz0[6]*i0, nz0[7]*i0};
  f32x4 rc = {nz1[0]*i1, nz1[1]*i1, nz1[2]*i1, nz1[3]*i1};
  f32x4 rd = {nz1[4]*i1, nz1[5]*i1, nz1[6]*i1, nz1[7]*i1};
  *(f32x4*)(dst + o0) = ra; *(f32x4*)(dst + o0 + 4) = rb;
  *(f32x4*)(dst + o1) = rc; *(f32x4*)(dst + o1 + 4) = rd;
}

extern "C" void kernel_launch(void* const* d_in, const int* in_sizes, int n_in,
                              void* d_out, int out_size, void* d_ws, size_t ws_size,
                              hipStream_t stream) {
  const float* z  = (const float*)d_in[0];
  const float* ck = (const float*)d_in[1];
  const float* cb = (const float*)d_in[2];
  const float* Wq = (const float*)d_in[3];
  const float* bq = (const float*)d_in[4];
  const float* Wk = (const float*)d_in[5];
  const float* bk = (const float*)d_in[6];
  const float* Wo = (const float*)d_in[7];
  const float* bo = (const float*)d_in[8];
  float* out = (float*)d_out;

  float* mf   = (float*)d_ws;          // [B,T,D] f32
  float* zc   = mf   + NELT;
  float* att  = zc   + NELT;
  float* vsum = att  + NELT;
  f16*   khb  = (f16*)(vsum + NELT);   // fp16 [B,T,D]
  f16*   khT  = khb  + NELT;           // fp16 [B,D,T]
  f16*   qhb  = khT  + NELT;           // fp16 [B,T,D]
  f16*   part = qhb  + NELT;           // [BB*NCHUNK][128][128] fp16 partials (~34.6 MB)

  k_proj<<<NROW/32, 256, 0, stream>>>(z, Wk, bk, khb, khT);
  k_conv<<<BB*TT/16, 256, 0, stream>>>(z, ck, cb, mf);

  const float wv[4] = {1.f, 2.f, 2.f, 1.f};
  const float cv[4] = {0.5f, 0.5f, 1.f, 0.f};
  for (int st = 0; st < 4; st++){
    const float* zcur = (st == 0) ? z : zc;
    k_q     <<<NROW/32, 256, 0, stream>>>(zcur, Wq, bq, qhb);
    k_attn11<<<BB*NCHUNK, 256, 0, stream>>>(qhb, khb, khT, part);
    k_reduce<<<BB*NQT3*8, 256, 0, stream>>>(part, att);
    k_comb  <<<NROW/32, 256, 0, stream>>>(z, Wo, bo, mf, att, zcur, zc, vsum, out,
                                          wv[st], cv[st], st == 0, st == 3);
  }
}

// Round 17
// 302.885 us; speedup vs baseline: 1.0873x; 1.0873x over previous
//
#include <hip/hip_runtime.h>
#include <hip/hip_bf16.h>

#define BB 2
#define TT 4096
#define DD 128
#define KK 256
#define NROW (BB*TT)    // 8192 rows
#define NELT (NROW*DD)  // 1048576 elements per [B,T,D] buffer

typedef _Float16 f16;
typedef __attribute__((ext_vector_type(8))) f16 half8;
typedef __attribute__((ext_vector_type(2))) __fp16 fp16x2;
typedef __attribute__((ext_vector_type(4))) float f32x4;
typedef __attribute__((ext_vector_type(2))) int i32x2;

__device__ __forceinline__ int pack2(float a, float b){
  fp16x2 h = __builtin_amdgcn_cvt_pkrtz(a, b);
  return __builtin_bit_cast(int, h);
}

// ================= k_proj: k_hat = normalize(z@Wk+bk) -> fp16 [T][D] and [D][T] =================
__global__ __launch_bounds__(256) void k_proj(
    const float* __restrict__ z, const float* __restrict__ Wk, const float* __restrict__ bk,
    f16* __restrict__ khb, f16* __restrict__ khT)
{
  __shared__ float Ws[DD*DD];
  __shared__ float zs[32*DD];
  int tid = threadIdx.x;
  int r0 = blockIdx.x * 32;
  #pragma unroll
  for (int it = 0; it < 16; it++){
    int idx = tid + it*256;
    *(f32x4*)(Ws + idx*4) = *(const f32x4*)(Wk + (size_t)idx*4);
  }
  #pragma unroll
  for (int it = 0; it < 4; it++){
    int idx = tid + it*256;
    *(f32x4*)(zs + idx*4) = *(const f32x4*)(z + (size_t)r0*DD + idx*4);
  }
  __syncthreads();
  int c = tid & 15, rr = tid >> 4;
  float acc0[8], acc1[8];
  #pragma unroll
  for (int u = 0; u < 8; u++){ float bv = bk[c*8+u]; acc0[u] = bv; acc1[u] = bv; }
  const float* zr0 = zs + rr*DD;
  const float* zr1 = zs + (rr+16)*DD;
  #pragma unroll 4
  for (int i = 0; i < DD; i++){
    f32x4 w0 = *(const f32x4*)(Ws + i*DD + c*8);
    f32x4 w1 = *(const f32x4*)(Ws + i*DD + c*8 + 4);
    float a0 = zr0[i], a1 = zr1[i];
    #pragma unroll
    for (int u = 0; u < 4; u++){
      acc0[u]   = fmaf(a0, w0[u], acc0[u]);   acc1[u]   = fmaf(a1, w0[u], acc1[u]);
      acc0[4+u] = fmaf(a0, w1[u], acc0[4+u]); acc1[4+u] = fmaf(a1, w1[u], acc1[4+u]);
    }
  }
  float s0 = 0.f, s1 = 0.f;
  #pragma unroll
  for (int u = 0; u < 8; u++){ s0 = fmaf(acc0[u], acc0[u], s0); s1 = fmaf(acc1[u], acc1[u], s1); }
  #pragma unroll
  for (int m = 1; m < 16; m <<= 1){ s0 += __shfl_xor(s0, m, 16); s1 += __shfl_xor(s1, m, 16); }
  float inv0 = 1.f / fmaxf(sqrtf(s0), 1e-8f);
  float inv1 = 1.f / fmaxf(sqrtf(s1), 1e-8f);
  half8 h0, h1;
  #pragma unroll
  for (int u = 0; u < 8; u++){ h0[u] = (f16)(acc0[u]*inv0); h1[u] = (f16)(acc1[u]*inv1); }
  int row0 = r0 + rr, row1 = row0 + 16;
  *(half8*)(khb + (size_t)row0*DD + c*8) = h0;
  *(half8*)(khb + (size_t)row1*DD + c*8) = h1;
  int b = row0 >> 12, t0 = row0 & 4095, t1 = row1 & 4095;
  #pragma unroll
  for (int u = 0; u < 8; u++){
    khT[((size_t)b*DD + c*8 + u)*TT + t0] = h0[u];
    khT[((size_t)b*DD + c*8 + u)*TT + t1] = h1[u];
  }
}

// ================= k_conv: causal depthwise conv, register sliding window =================
__global__ __launch_bounds__(256) void k_conv(
    const float* __restrict__ z, const float* __restrict__ ck, const float* __restrict__ cb,
    float* __restrict__ mf)
{
  int tid = threadIdx.x;
  int d = tid & 127, tg = tid >> 7;
  int bid = blockIdx.x;
  int b = bid >> 8;
  int tbase = ((bid & 255) << 4) + tg*8;
  const float* zb = z + (size_t)b*TT*DD;
  float acc[8];
  #pragma unroll
  for (int j = 0; j < 8; j++) acc[j] = 0.f;
  float ckq[8];
  #pragma unroll
  for (int u = 0; u < 8; u++) ckq[u] = 0.f;
  int sstart = tbase - (KK-1);
  for (int ch = 0; ch < 33; ch++){
    #pragma unroll
    for (int u = 0; u < 8; u++){
      int base = ch*8 + u;
      int s = sstart + base;
      float zv = ((unsigned)s < (unsigned)TT && base < 263) ? zb[(size_t)s*DD + d] : 0.f;
      ckq[u] = (base < KK) ? ck[(size_t)base*DD + d] : 0.f;
      #pragma unroll
      for (int j = 0; j < 8; j++) acc[j] = fmaf(ckq[(u-j)&7], zv, acc[j]);
    }
  }
  float cbv = cb[d];
  #pragma unroll
  for (int j = 0; j < 8; j++)
    mf[((size_t)b*TT + tbase + j)*DD + d] = acc[j] + cbv;
}

// ================= k_q: q_hat = normalize(zcur@Wq+bq) -> fp16 =================
__global__ __launch_bounds__(256) void k_q(
    const float* __restrict__ zcur, const float* __restrict__ Wq, const float* __restrict__ bq,
    f16* __restrict__ qhb)
{
  __shared__ float Ws[DD*DD];
  __shared__ float zs[32*DD];
  int tid = threadIdx.x;
  int r0 = blockIdx.x * 32;
  #pragma unroll
  for (int it = 0; it < 16; it++){
    int idx = tid + it*256;
    *(f32x4*)(Ws + idx*4) = *(const f32x4*)(Wq + (size_t)idx*4);
  }
  #pragma unroll
  for (int it = 0; it < 4; it++){
    int idx = tid + it*256;
    *(f32x4*)(zs + idx*4) = *(const f32x4*)(zcur + (size_t)r0*DD + idx*4);
  }
  __syncthreads();
  int c = tid & 15, rr = tid >> 4;
  float acc0[8], acc1[8];
  #pragma unroll
  for (int u = 0; u < 8; u++){ float bv = bq[c*8+u]; acc0[u] = bv; acc1[u] = bv; }
  const float* zr0 = zs + rr*DD;
  const float* zr1 = zs + (rr+16)*DD;
  #pragma unroll 4
  for (int i = 0; i < DD; i++){
    f32x4 w0 = *(const f32x4*)(Ws + i*DD + c*8);
    f32x4 w1 = *(const f32x4*)(Ws + i*DD + c*8 + 4);
    float a0 = zr0[i], a1 = zr1[i];
    #pragma unroll
    for (int u = 0; u < 4; u++){
      acc0[u]   = fmaf(a0, w0[u], acc0[u]);   acc1[u]   = fmaf(a1, w0[u], acc1[u]);
      acc0[4+u] = fmaf(a0, w1[u], acc0[4+u]); acc1[4+u] = fmaf(a1, w1[u], acc1[4+u]);
    }
  }
  float s0 = 0.f, s1 = 0.f;
  #pragma unroll
  for (int u = 0; u < 8; u++){ s0 = fmaf(acc0[u], acc0[u], s0); s1 = fmaf(acc1[u], acc1[u], s1); }
  #pragma unroll
  for (int m = 1; m < 16; m <<= 1){ s0 += __shfl_xor(s0, m, 16); s1 += __shfl_xor(s1, m, 16); }
  float inv0 = 1.f / fmaxf(sqrtf(s0), 1e-8f);
  float inv1 = 1.f / fmaxf(sqrtf(s1), 1e-8f);
  half8 h0, h1;
  #pragma unroll
  for (int u = 0; u < 8; u++){ h0[u] = (f16)(acc0[u]*inv0); h1[u] = (f16)(acc1[u]*inv1); }
  *(half8*)(qhb + (size_t)(r0+rr)*DD + c*8) = h0;
  *(half8*)(qhb + (size_t)(r0+rr+16)*DD + c*8) = h1;
}

// ====== MFMA attention v12: R13 core, chunks of 8 key-tiles (288 blocks, <=8 iters/block) ======
#define QTILE 128
#define NQT3 (TT/QTILE)     // 32 q-tiles per batch
#define NCHUNK 144          // sum_{qt=0}^{31} ceil((qt+1)/4)

__global__ __launch_bounds__(256,2) void k_attn12(
    const f16* __restrict__ qhb, const f16* __restrict__ khb,
    const f16* __restrict__ khT, f16* __restrict__ part)
{
  int bid = blockIdx.x;
  int b = bid / NCHUNK;
  int rem = bid - b*NCHUNK;
  int qt = 0, chunk = 0;
  #pragma unroll 1
  for (int j = 0; j < NQT3; j++){
    int nch = (j + 4) >> 2;     // ceil((j+1)/4) chunks of 8 key-tiles
    if (rem < nch){ qt = j; chunk = rem; break; }
    rem -= nch;
  }
  int kt0 = chunk * 8;
  int kt1 = min(kt0 + 7, 2*qt + 1);
  int t0 = qt * QTILE;

  __shared__ __align__(16) f16 Kb[64*136];     // [key][dim],  stride 136 (17408 B)
  __shared__ __align__(16) f16 Kt[128*72];     // [dim][key],  stride 72  (18432 B)
  __shared__ __align__(16) f16 Ps[4][32*72];   // per-wave P fp16, [q][key], stride 72 (18432 B)

  int tid  = threadIdx.x;
  int w    = tid >> 6;
  int lane = tid & 63;
  int n16  = lane & 15;
  int g    = lane >> 4;

  const f16* qg  = qhb + (size_t)b*TT*DD;
  const f16* kg  = khb + (size_t)b*TT*DD;
  const f16* ktg = khT + (size_t)b*DD*TT;

  int sb_r  = tid >> 4, sb_c = (tid & 15)*8;   // Kb staging base
  int st_r  = tid >> 3, st_c = (tid & 7)*8;    // Kt staging base

  half8 qa[2][4];   // Q rows; used as MFMA B-operand (A/B lane maps identical for 16x16x32 f16)
  #pragma unroll
  for (int p = 0; p < 2; p++){
    const f16* qrow = qg + (size_t)(t0 + 32*w + 16*p + n16)*DD + g*8;
    #pragma unroll
    for (int c = 0; c < 4; c++) qa[p][c] = *(const half8*)(qrow + 32*c);
  }
  f32x4 acc[2][8];
  #pragma unroll
  for (int p = 0; p < 2; p++)
    #pragma unroll
    for (int i = 0; i < 8; i++) acc[p][i] = (f32x4){0.f,0.f,0.f,0.f};

  f16* psw = &Ps[w][0];

  // ---- register prefetch of first K tile ----
  half8 sKb[4], sKt[4];
  {
    int s0 = kt0 * 64;
    #pragma unroll
    for (int it = 0; it < 4; it++)
      sKb[it] = *(const half8*)(kg + (size_t)(s0 + sb_r + it*16)*DD + sb_c);
    #pragma unroll
    for (int it = 0; it < 4; it++)
      sKt[it] = *(const half8*)(ktg + (size_t)(st_r + it*32)*TT + s0 + st_c);
  }

  for (int kt = kt0; kt <= kt1; kt++){
    #pragma unroll
    for (int it = 0; it < 4; it++)
      *(half8*)(Kb + (sb_r + it*16)*136 + sb_c) = sKb[it];
    #pragma unroll
    for (int it = 0; it < 4; it++)
      *(half8*)(Kt + (st_r + it*32)*72 + st_c) = sKt[it];
    __syncthreads();

    if (kt < kt1){
      int s0n = (kt+1) * 64;
      #pragma unroll
      for (int it = 0; it < 4; it++)
        sKb[it] = *(const half8*)(kg + (size_t)(s0n + sb_r + it*16)*DD + sb_c);
      #pragma unroll
      for (int it = 0; it < 4; it++)
        sKt[it] = *(const half8*)(ktg + (size_t)(st_r + it*32)*TT + s0n + st_c);
    }

    int s0 = kt * 64;
    // ---- QK^T transposed: A = K rows (Kb), B = Q regs -> S^T[m=key][n=query] ----
    f32x4 s_acc[2][4];
    #pragma unroll
    for (int p = 0; p < 2; p++)
      #pragma unroll
      for (int n = 0; n < 4; n++) s_acc[p][n] = (f32x4){0.f,0.f,0.f,0.f};
    #pragma unroll
    for (int c = 0; c < 4; c++){
      #pragma unroll
      for (int n = 0; n < 4; n++){
        half8 af = *(const half8*)(Kb + (16*n + n16)*136 + 32*c + g*8);
        s_acc[0][n] = __builtin_amdgcn_mfma_f32_16x16x32_f16(af, qa[0][c], s_acc[0][n], 0,0,0);
        s_acc[1][n] = __builtin_amdgcn_mfma_f32_16x16x32_f16(af, qa[1][c], s_acc[1][n], 0,0,0);
      }
    }
    // ---- sin + mask; lane holds q=n16, keys 16n+4g+r -> pack 4 keys -> ONE b64 write ----
    #pragma unroll
    for (int p = 0; p < 2; p++){
      int qrow = t0 + 32*w + 16*p + n16;
      #pragma unroll
      for (int n = 0; n < 4; n++){
        int keyr = s0 + 16*n + 4*g;
        float v0 = (keyr     <= qrow) ? __sinf(s_acc[p][n][0]) : 0.f;
        float v1 = (keyr + 1 <= qrow) ? __sinf(s_acc[p][n][1]) : 0.f;
        float v2 = (keyr + 2 <= qrow) ? __sinf(s_acc[p][n][2]) : 0.f;
        float v3 = (keyr + 3 <= qrow) ? __sinf(s_acc[p][n][3]) : 0.f;
        i32x2 pw = { pack2(v0, v1), pack2(v2, v3) };
        *(i32x2*)(psw + (16*p + n16)*72 + 16*n + 4*g) = pw;
      }
    }
    // intra-wave RAW on psw ordered by lgkmcnt (per-wave buffer, no barrier)

    // ---- PV: A = P rows (Ps[q][key] b128), B = Kt rows -> O[q][dim] ----
    #pragma unroll
    for (int h = 0; h < 2; h++){
      half8 pa[2];
      #pragma unroll
      for (int p = 0; p < 2; p++)
        pa[p] = *(const half8*)(psw + (16*p + n16)*72 + 32*h + 8*g);
      #pragma unroll
      for (int nt = 0; nt < 8; nt++){
        half8 bf = *(const half8*)(Kt + (16*nt + n16)*72 + 32*h + 8*g);
        acc[0][nt] = __builtin_amdgcn_mfma_f32_16x16x32_f16(pa[0], bf, acc[0][nt], 0,0,0);
        acc[1][nt] = __builtin_amdgcn_mfma_f32_16x16x32_f16(pa[1], bf, acc[1][nt], 0,0,0);
      }
    }
    __syncthreads();   // protect Kb/Kt/psw before next staging
  }

  // ---- epilogue: fp16 partial store ([q][dim] contiguous per chunk) ----
  f16* pb = part + (size_t)bid*(QTILE*DD) + (32*w)*DD;
  #pragma unroll
  for (int p = 0; p < 2; p++){
    #pragma unroll
    for (int nt = 0; nt < 8; nt++){
      #pragma unroll
      for (int r = 0; r < 4; r++){
        pb[(size_t)(16*p + 4*g + r)*DD + 16*nt + n16] = (f16)acc[p][nt][r];
      }
    }
  }
}

// ================= k_reduce: att[b,qtile rows,:] = sum of fp16 partials (f32 accum) ===========
__global__ __launch_bounds__(256) void k_reduce(
    const f16* __restrict__ part, float* __restrict__ att)
{
  int bid = blockIdx.x;            // BB * 32 * 8 blocks
  int rg = bid & 7;
  int qt = (bid >> 3) & 31;
  int b  = bid >> 8;
  int nc = (qt + 4) >> 2;          // chunks of 8 key-tiles
  int base = 0;
  #pragma unroll 1
  for (int j = 0; j < qt; j++) base += (j + 4) >> 2;
  int tid = threadIdx.x;
  size_t off = (size_t)rg*(16*DD) + tid*8;
  const f16* src = part + ((size_t)b*NCHUNK + base)*(QTILE*DD) + off;
  float a[8];
  {
    half8 v = *(const half8*)(src);
    #pragma unroll
    for (int u = 0; u < 8; u++) a[u] = (float)v[u];
  }
  for (int c = 1; c < nc; c++){
    half8 v = *(const half8*)(src + (size_t)c*(QTILE*DD));
    #pragma unroll
    for (int u = 0; u < 8; u++) a[u] += (float)v[u];
  }
  float* dst = att + ((size_t)b*TT + (size_t)qt*QTILE)*DD + off;
  f32x4 o0 = {a[0],a[1],a[2],a[3]}, o1 = {a[4],a[5],a[6],a[7]};
  *(f32x4*)(dst) = o0;
  *(f32x4*)(dst + 4) = o1;
}

// ================= k_comb: ki = proj(mf + att@Wo + bo); vsum += w*ki; retract =================
__global__ __launch_bounds__(256) void k_comb(
    const float* __restrict__ z, const float* __restrict__ Wo, const float* __restrict__ bo,
    const float* __restrict__ mf, const float* __restrict__ att,
    const float* __restrict__ zin, float* __restrict__ zout,
    float* __restrict__ vsum, float* __restrict__ out,
    float wsum, float cretr, int first, int last)
{
  __shared__ float Ws[DD*DD];
  __shared__ float As[32*DD];
  int tid = threadIdx.x;
  int r0 = blockIdx.x * 32;
  #pragma unroll
  for (int it = 0; it < 16; it++){
    int idx = tid + it*256;
    *(f32x4*)(Ws + idx*4) = *(const f32x4*)(Wo + (size_t)idx*4);
  }
  #pragma unroll
  for (int it = 0; it < 4; it++){
    int idx = tid + it*256;
    *(f32x4*)(As + idx*4) = *(const f32x4*)(att + (size_t)r0*DD + idx*4);
  }
  __syncthreads();
  int c = tid & 15, rr = tid >> 4;
  float kur0[8], kur1[8];
  #pragma unroll
  for (int u = 0; u < 8; u++){ float bv = bo[c*8+u]; kur0[u] = bv; kur1[u] = bv; }
  const float* ar0 = As + rr*DD;
  const float* ar1 = As + (rr+16)*DD;
  #pragma unroll 4
  for (int i = 0; i < DD; i++){
    f32x4 w0 = *(const f32x4*)(Ws + i*DD + c*8);
    f32x4 w1 = *(const f32x4*)(Ws + i*DD + c*8 + 4);
    float a0 = ar0[i], a1 = ar1[i];
    #pragma unroll
    for (int u = 0; u < 4; u++){
      kur0[u]   = fmaf(a0, w0[u], kur0[u]);   kur1[u]   = fmaf(a1, w0[u], kur1[u]);
      kur0[4+u] = fmaf(a0, w1[u], kur0[4+u]); kur1[4+u] = fmaf(a1, w1[u], kur1[4+u]);
    }
  }
  size_t o0 = (size_t)(r0+rr)*DD + c*8;
  size_t o1 = (size_t)(r0+rr+16)*DD + c*8;
  float tot0[8], tot1[8], zi0[8], zi1[8];
  {
    f32x4 m0a = *(const f32x4*)(mf + o0), m0b = *(const f32x4*)(mf + o0 + 4);
    f32x4 m1a = *(const f32x4*)(mf + o1), m1b = *(const f32x4*)(mf + o1 + 4);
    f32x4 z0a = *(const f32x4*)(zin + o0), z0b = *(const f32x4*)(zin + o0 + 4);
    f32x4 z1a = *(const f32x4*)(zin + o1), z1b = *(const f32x4*)(zin + o1 + 4);
    #pragma unroll
    for (int u = 0; u < 4; u++){
      tot0[u] = m0a[u] + kur0[u]; tot0[4+u] = m0b[u] + kur0[4+u];
      tot1[u] = m1a[u] + kur1[u]; tot1[4+u] = m1b[u] + kur1[4+u];
      zi0[u] = z0a[u]; zi0[4+u] = z0b[u];
      zi1[u] = z1a[u]; zi1[4+u] = z1b[u];
    }
  }
  float p0 = 0.f, p1 = 0.f;
  #pragma unroll
  for (int u = 0; u < 8; u++){ p0 = fmaf(tot0[u], zi0[u], p0); p1 = fmaf(tot1[u], zi1[u], p1); }
  #pragma unroll
  for (int m = 1; m < 16; m <<= 1){ p0 += __shfl_xor(p0, m, 16); p1 += __shfl_xor(p1, m, 16); }
  float ki0[8], ki1[8], vs0[8], vs1[8];
  #pragma unroll
  for (int u = 0; u < 8; u++){
    ki0[u] = tot0[u] - p0 * zi0[u];
    ki1[u] = tot1[u] - p1 * zi1[u];
  }
  if (first){
    #pragma unroll
    for (int u = 0; u < 8; u++){ vs0[u] = wsum*ki0[u]; vs1[u] = wsum*ki1[u]; }
  } else {
    f32x4 v0a = *(const f32x4*)(vsum + o0), v0b = *(const f32x4*)(vsum + o0 + 4);
    f32x4 v1a = *(const f32x4*)(vsum + o1), v1b = *(const f32x4*)(vsum + o1 + 4);
    #pragma unroll
    for (int u = 0; u < 4; u++){
      vs0[u] = fmaf(wsum, ki0[u], v0a[u]); vs0[4+u] = fmaf(wsum, ki0[4+u], v0b[u]);
      vs1[u] = fmaf(wsum, ki1[u], v1a[u]); vs1[4+u] = fmaf(wsum, ki1[4+u], v1b[u]);
    }
  }
  if (!last){
    f32x4 va = {vs0[0],vs0[1],vs0[2],vs0[3]}, vb = {vs0[4],vs0[5],vs0[6],vs0[7]};
    f32x4 vc = {vs1[0],vs1[1],vs1[2],vs1[3]}, vd = {vs1[4],vs1[5],vs1[6],vs1[7]};
    *(f32x4*)(vsum + o0) = va; *(f32x4*)(vsum + o0 + 4) = vb;
    *(f32x4*)(vsum + o1) = vc; *(f32x4*)(vsum + o1 + 4) = vd;
  }
  float nz0[8], nz1[8];
  {
    f32x4 z0a = *(const f32x4*)(z + o0), z0b = *(const f32x4*)(z + o0 + 4);
    f32x4 z1a = *(const f32x4*)(z + o1), z1b = *(const f32x4*)(z + o1 + 4);
    #pragma unroll
    for (int u = 0; u < 4; u++){
      float d0a = last ? vs0[u]*(1.f/6.f)   : cretr*ki0[u];
      float d0b = last ? vs0[4+u]*(1.f/6.f) : cretr*ki0[4+u];
      float d1a = last ? vs1[u]*(1.f/6.f)   : cretr*ki1[u];
      float d1b = last ? vs1[4+u]*(1.f/6.f) : cretr*ki1[4+u];
      nz0[u] = z0a[u] + d0a; nz0[4+u] = z0b[u] + d0b;
      nz1[u] = z1a[u] + d1a; nz1[4+u] = z1b[u] + d1b;
    }
  }
  float n0 = 0.f, n1 = 0.f;
  #pragma unroll
  for (int u = 0; u < 8; u++){ n0 = fmaf(nz0[u], nz0[u], n0); n1 = fmaf(nz1[u], nz1[u], n1); }
  #pragma unroll
  for (int m = 1; m < 16; m <<= 1){ n0 += __shfl_xor(n0, m, 16); n1 += __shfl_xor(n1, m, 16); }
  float i0 = 1.f / fmaxf(sqrtf(n0), 1e-8f);
  float i1 = 1.f / fmaxf(sqrtf(n1), 1e-8f);
  float* dst = last ? out : zout;
  f32x4 ra = {nz0[0]*i0, nz0[1]*i0, nz0[2]*i0, nz0[3]*i0};
  f32x4 rb = {nz0[4]*i0, nz0[5]*i0, nz0[6]*i0, nz0[7]*i0};
  f32x4 rc = {nz1[0]*i1, nz1[1]*i1, nz1[2]*i1, nz1[3]*i1};
  f32x4 rd = {nz1[4]*i1, nz1[5]*i1, nz1[6]*i1, nz1[7]*i1};
  *(f32x4*)(dst + o0) = ra; *(f32x4*)(dst + o0 + 4) = rb;
  *(f32x4*)(dst + o1) = rc; *(f32x4*)(dst + o1 + 4) = rd;
}

extern "C" void kernel_launch(void* const* d_in, const int* in_sizes, int n_in,
                              void* d_out, int out_size, void* d_ws, size_t ws_size,
                              hipStream_t stream) {
  const float* z  = (const float*)d_in[0];
  const float* ck = (const float*)d_in[1];
  const float* cb = (const float*)d_in[2];
  const float* Wq = (const float*)d_in[3];
  const float* bq = (const float*)d_in[4];
  const float* Wk = (const float*)d_in[5];
  const float* bk = (const float*)d_in[6];
  const float* Wo = (const float*)d_in[7];
  const float* bo = (const float*)d_in[8];
  float* out = (float*)d_out;

  float* mf   = (float*)d_ws;          // [B,T,D] f32
  float* zc   = mf   + NELT;
  float* att  = zc   + NELT;
  float* vsum = att  + NELT;
  f16*   khb  = (f16*)(vsum + NELT);   // fp16 [B,T,D]
  f16*   khT  = khb  + NELT;           // fp16 [B,D,T]
  f16*   qhb  = khT  + NELT;           // fp16 [B,T,D]
  f16*   part = qhb  + NELT;           // [BB*NCHUNK][128][128] fp16 partials (~9.4 MB)

  k_proj<<<NROW/32, 256, 0, stream>>>(z, Wk, bk, khb, khT);
  k_conv<<<BB*TT/16, 256, 0, stream>>>(z, ck, cb, mf);

  const float wv[4] = {1.f, 2.f, 2.f, 1.f};
  const float cv[4] = {0.5f, 0.5f, 1.f, 0.f};
  for (int st = 0; st < 4; st++){
    const float* zcur = (st == 0) ? z : zc;
    k_q     <<<NROW/32, 256, 0, stream>>>(zcur, Wq, bq, qhb);
    k_attn12<<<BB*NCHUNK, 256, 0, stream>>>(qhb, khb, khT, part);
    k_reduce<<<BB*NQT3*8, 256, 0, stream>>>(part, att);
    k_comb  <<<NROW/32, 256, 0, stream>>>(z, Wo, bo, mf, att, zcur, zc, vsum, out,
                                          wv[st], cv[st], st == 0, st == 3);
  }
}

// Round 18
// 298.395 us; speedup vs baseline: 1.1037x; 1.0150x over previous
//
#include <hip/hip_runtime.h>
#include <hip/hip_bf16.h>

#define BB 2
#define TT 4096
#define DD 128
#define KK 256
#define NROW (BB*TT)    // 8192 rows
#define NELT (NROW*DD)  // 1048576 elements per [B,T,D] buffer

typedef _Float16 f16;
typedef __attribute__((ext_vector_type(8))) f16 half8;
typedef __attribute__((ext_vector_type(2))) __fp16 fp16x2;
typedef __attribute__((ext_vector_type(4))) float f32x4;
typedef __attribute__((ext_vector_type(2))) int i32x2;

__device__ __forceinline__ int pack2(float a, float b){
  fp16x2 h = __builtin_amdgcn_cvt_pkrtz(a, b);
  return __builtin_bit_cast(int, h);
}

// ======== k_prep: merged one-shot. blocks 0..255: k_hat proj; blocks 256..767: causal conv ====
__global__ __launch_bounds__(256) void k_prep(
    const float* __restrict__ z, const float* __restrict__ Wk, const float* __restrict__ bk,
    const float* __restrict__ ck, const float* __restrict__ cb,
    f16* __restrict__ khb, f16* __restrict__ khT, float* __restrict__ mf)
{
  int tid = threadIdx.x;
  if (blockIdx.x < 256){
    // ---- proj: k_hat = normalize(z@Wk+bk) -> fp16 [T][D] and [D][T] ----
    __shared__ float Ws[DD*DD];
    __shared__ float zs[32*DD];
    int r0 = blockIdx.x * 32;
    #pragma unroll
    for (int it = 0; it < 16; it++){
      int idx = tid + it*256;
      *(f32x4*)(Ws + idx*4) = *(const f32x4*)(Wk + (size_t)idx*4);
    }
    #pragma unroll
    for (int it = 0; it < 4; it++){
      int idx = tid + it*256;
      *(f32x4*)(zs + idx*4) = *(const f32x4*)(z + (size_t)r0*DD + idx*4);
    }
    __syncthreads();
    int c = tid & 15, rr = tid >> 4;
    float acc0[8], acc1[8];
    #pragma unroll
    for (int u = 0; u < 8; u++){ float bv = bk[c*8+u]; acc0[u] = bv; acc1[u] = bv; }
    const float* zr0 = zs + rr*DD;
    const float* zr1 = zs + (rr+16)*DD;
    #pragma unroll 4
    for (int i = 0; i < DD; i++){
      f32x4 w0 = *(const f32x4*)(Ws + i*DD + c*8);
      f32x4 w1 = *(const f32x4*)(Ws + i*DD + c*8 + 4);
      float a0 = zr0[i], a1 = zr1[i];
      #pragma unroll
      for (int u = 0; u < 4; u++){
        acc0[u]   = fmaf(a0, w0[u], acc0[u]);   acc1[u]   = fmaf(a1, w0[u], acc1[u]);
        acc0[4+u] = fmaf(a0, w1[u], acc0[4+u]); acc1[4+u] = fmaf(a1, w1[u], acc1[4+u]);
      }
    }
    float s0 = 0.f, s1 = 0.f;
    #pragma unroll
    for (int u = 0; u < 8; u++){ s0 = fmaf(acc0[u], acc0[u], s0); s1 = fmaf(acc1[u], acc1[u], s1); }
    #pragma unroll
    for (int m = 1; m < 16; m <<= 1){ s0 += __shfl_xor(s0, m, 16); s1 += __shfl_xor(s1, m, 16); }
    float inv0 = 1.f / fmaxf(sqrtf(s0), 1e-8f);
    float inv1 = 1.f / fmaxf(sqrtf(s1), 1e-8f);
    half8 h0, h1;
    #pragma unroll
    for (int u = 0; u < 8; u++){ h0[u] = (f16)(acc0[u]*inv0); h1[u] = (f16)(acc1[u]*inv1); }
    int row0 = r0 + rr, row1 = row0 + 16;
    *(half8*)(khb + (size_t)row0*DD + c*8) = h0;
    *(half8*)(khb + (size_t)row1*DD + c*8) = h1;
    int b = row0 >> 12, t0 = row0 & 4095, t1 = row1 & 4095;
    #pragma unroll
    for (int u = 0; u < 8; u++){
      khT[((size_t)b*DD + c*8 + u)*TT + t0] = h0[u];
      khT[((size_t)b*DD + c*8 + u)*TT + t1] = h1[u];
    }
  } else {
    // ---- conv: register sliding window ----
    int bid = blockIdx.x - 256;
    int d = tid & 127, tg = tid >> 7;
    int b = bid >> 8;
    int tbase = ((bid & 255) << 4) + tg*8;
    const float* zb = z + (size_t)b*TT*DD;
    float acc[8];
    #pragma unroll
    for (int j = 0; j < 8; j++) acc[j] = 0.f;
    float ckq[8];
    #pragma unroll
    for (int u = 0; u < 8; u++) ckq[u] = 0.f;
    int sstart = tbase - (KK-1);
    for (int ch = 0; ch < 33; ch++){
      #pragma unroll
      for (int u = 0; u < 8; u++){
        int base = ch*8 + u;
        int s = sstart + base;
        float zv = ((unsigned)s < (unsigned)TT && base < 263) ? zb[(size_t)s*DD + d] : 0.f;
        ckq[u] = (base < KK) ? ck[(size_t)base*DD + d] : 0.f;
        #pragma unroll
        for (int j = 0; j < 8; j++) acc[j] = fmaf(ckq[(u-j)&7], zv, acc[j]);
      }
    }
    float cbv = cb[d];
    #pragma unroll
    for (int j = 0; j < 8; j++)
      mf[((size_t)b*TT + tbase + j)*DD + d] = acc[j] + cbv;
  }
}

// ================= k_q: q_hat = normalize(zcur@Wq+bq) -> fp16 =================
__global__ __launch_bounds__(256) void k_q(
    const float* __restrict__ zcur, const float* __restrict__ Wq, const float* __restrict__ bq,
    f16* __restrict__ qhb)
{
  __shared__ float Ws[DD*DD];
  __shared__ float zs[32*DD];
  int tid = threadIdx.x;
  int r0 = blockIdx.x * 32;
  #pragma unroll
  for (int it = 0; it < 16; it++){
    int idx = tid + it*256;
    *(f32x4*)(Ws + idx*4) = *(const f32x4*)(Wq + (size_t)idx*4);
  }
  #pragma unroll
  for (int it = 0; it < 4; it++){
    int idx = tid + it*256;
    *(f32x4*)(zs + idx*4) = *(const f32x4*)(zcur + (size_t)r0*DD + idx*4);
  }
  __syncthreads();
  int c = tid & 15, rr = tid >> 4;
  float acc0[8], acc1[8];
  #pragma unroll
  for (int u = 0; u < 8; u++){ float bv = bq[c*8+u]; acc0[u] = bv; acc1[u] = bv; }
  const float* zr0 = zs + rr*DD;
  const float* zr1 = zs + (rr+16)*DD;
  #pragma unroll 4
  for (int i = 0; i < DD; i++){
    f32x4 w0 = *(const f32x4*)(Ws + i*DD + c*8);
    f32x4 w1 = *(const f32x4*)(Ws + i*DD + c*8 + 4);
    float a0 = zr0[i], a1 = zr1[i];
    #pragma unroll
    for (int u = 0; u < 4; u++){
      acc0[u]   = fmaf(a0, w0[u], acc0[u]);   acc1[u]   = fmaf(a1, w0[u], acc1[u]);
      acc0[4+u] = fmaf(a0, w1[u], acc0[4+u]); acc1[4+u] = fmaf(a1, w1[u], acc1[4+u]);
    }
  }
  float s0 = 0.f, s1 = 0.f;
  #pragma unroll
  for (int u = 0; u < 8; u++){ s0 = fmaf(acc0[u], acc0[u], s0); s1 = fmaf(acc1[u], acc1[u], s1); }
  #pragma unroll
  for (int m = 1; m < 16; m <<= 1){ s0 += __shfl_xor(s0, m, 16); s1 += __shfl_xor(s1, m, 16); }
  float inv0 = 1.f / fmaxf(sqrtf(s0), 1e-8f);
  float inv1 = 1.f / fmaxf(sqrtf(s1), 1e-8f);
  half8 h0, h1;
  #pragma unroll
  for (int u = 0; u < 8; u++){ h0[u] = (f16)(acc0[u]*inv0); h1[u] = (f16)(acc1[u]*inv1); }
  *(half8*)(qhb + (size_t)(r0+rr)*DD + c*8) = h0;
  *(half8*)(qhb + (size_t)(r0+rr+16)*DD + c*8) = h1;
}

// ====== MFMA attention v13: chunks of 8 key-tiles, LPT order (qt descending with bid) ==========
#define QTILE 128
#define NQT3 (TT/QTILE)     // 32 q-tiles per batch
#define NCHUNK 144          // sum_{qt=0}^{31} ceil((qt+1)/4)

__global__ __launch_bounds__(256,2) void k_attn13(
    const f16* __restrict__ qhb, const f16* __restrict__ khb,
    const f16* __restrict__ khT, f16* __restrict__ part)
{
  int bid = blockIdx.x;
  int b = bid / NCHUNK;
  int rem = bid - b*NCHUNK;
  int qt = 0, chunk = 0;
  // LPT: large qt (8-iter blocks) first
  #pragma unroll 1
  for (int j = NQT3-1; j >= 0; j--){
    int nch = (j + 4) >> 2;     // ceil((j+1)/4)
    if (rem < nch){ qt = j; chunk = rem; break; }
    rem -= nch;
  }
  int kt0 = chunk * 8;
  int kt1 = min(kt0 + 7, 2*qt + 1);
  int t0 = qt * QTILE;

  __shared__ __align__(16) f16 Kb[64*136];     // [key][dim],  stride 136 (17408 B)
  __shared__ __align__(16) f16 Kt[128*72];     // [dim][key],  stride 72  (18432 B)
  __shared__ __align__(16) f16 Ps[4][32*72];   // per-wave P fp16, [q][key], stride 72 (18432 B)

  int tid  = threadIdx.x;
  int w    = tid >> 6;
  int lane = tid & 63;
  int n16  = lane & 15;
  int g    = lane >> 4;

  const f16* qg  = qhb + (size_t)b*TT*DD;
  const f16* kg  = khb + (size_t)b*TT*DD;
  const f16* ktg = khT + (size_t)b*DD*TT;

  int sb_r  = tid >> 4, sb_c = (tid & 15)*8;   // Kb staging base
  int st_r  = tid >> 3, st_c = (tid & 7)*8;    // Kt staging base

  half8 qa[2][4];   // Q rows; used as MFMA B-operand (A/B lane maps identical for 16x16x32 f16)
  #pragma unroll
  for (int p = 0; p < 2; p++){
    const f16* qrow = qg + (size_t)(t0 + 32*w + 16*p + n16)*DD + g*8;
    #pragma unroll
    for (int c = 0; c < 4; c++) qa[p][c] = *(const half8*)(qrow + 32*c);
  }
  f32x4 acc[2][8];
  #pragma unroll
  for (int p = 0; p < 2; p++)
    #pragma unroll
    for (int i = 0; i < 8; i++) acc[p][i] = (f32x4){0.f,0.f,0.f,0.f};

  f16* psw = &Ps[w][0];

  // ---- register prefetch of first K tile ----
  half8 sKb[4], sKt[4];
  {
    int s0 = kt0 * 64;
    #pragma unroll
    for (int it = 0; it < 4; it++)
      sKb[it] = *(const half8*)(kg + (size_t)(s0 + sb_r + it*16)*DD + sb_c);
    #pragma unroll
    for (int it = 0; it < 4; it++)
      sKt[it] = *(const half8*)(ktg + (size_t)(st_r + it*32)*TT + s0 + st_c);
  }

  for (int kt = kt0; kt <= kt1; kt++){
    #pragma unroll
    for (int it = 0; it < 4; it++)
      *(half8*)(Kb + (sb_r + it*16)*136 + sb_c) = sKb[it];
    #pragma unroll
    for (int it = 0; it < 4; it++)
      *(half8*)(Kt + (st_r + it*32)*72 + st_c) = sKt[it];
    __syncthreads();

    if (kt < kt1){
      int s0n = (kt+1) * 64;
      #pragma unroll
      for (int it = 0; it < 4; it++)
        sKb[it] = *(const half8*)(kg + (size_t)(s0n + sb_r + it*16)*DD + sb_c);
      #pragma unroll
      for (int it = 0; it < 4; it++)
        sKt[it] = *(const half8*)(ktg + (size_t)(st_r + it*32)*TT + s0n + st_c);
    }

    int s0 = kt * 64;
    // ---- QK^T transposed: A = K rows (Kb), B = Q regs -> S^T[m=key][n=query] ----
    f32x4 s_acc[2][4];
    #pragma unroll
    for (int p = 0; p < 2; p++)
      #pragma unroll
      for (int n = 0; n < 4; n++) s_acc[p][n] = (f32x4){0.f,0.f,0.f,0.f};
    #pragma unroll
    for (int c = 0; c < 4; c++){
      #pragma unroll
      for (int n = 0; n < 4; n++){
        half8 af = *(const half8*)(Kb + (16*n + n16)*136 + 32*c + g*8);
        s_acc[0][n] = __builtin_amdgcn_mfma_f32_16x16x32_f16(af, qa[0][c], s_acc[0][n], 0,0,0);
        s_acc[1][n] = __builtin_amdgcn_mfma_f32_16x16x32_f16(af, qa[1][c], s_acc[1][n], 0,0,0);
      }
    }
    // ---- sin + mask; lane holds q=n16, keys 16n+4g+r -> pack 4 keys -> ONE b64 write ----
    #pragma unroll
    for (int p = 0; p < 2; p++){
      int qrow = t0 + 32*w + 16*p + n16;
      #pragma unroll
      for (int n = 0; n < 4; n++){
        int keyr = s0 + 16*n + 4*g;
        float v0 = (keyr     <= qrow) ? __sinf(s_acc[p][n][0]) : 0.f;
        float v1 = (keyr + 1 <= qrow) ? __sinf(s_acc[p][n][1]) : 0.f;
        float v2 = (keyr + 2 <= qrow) ? __sinf(s_acc[p][n][2]) : 0.f;
        float v3 = (keyr + 3 <= qrow) ? __sinf(s_acc[p][n][3]) : 0.f;
        i32x2 pw = { pack2(v0, v1), pack2(v2, v3) };
        *(i32x2*)(psw + (16*p + n16)*72 + 16*n + 4*g) = pw;
      }
    }
    // intra-wave RAW on psw ordered by lgkmcnt (per-wave buffer, no barrier)

    // ---- PV: A = P rows (Ps[q][key] b128), B = Kt rows -> O[q][dim] ----
    #pragma unroll
    for (int h = 0; h < 2; h++){
      half8 pa[2];
      #pragma unroll
      for (int p = 0; p < 2; p++)
        pa[p] = *(const half8*)(psw + (16*p + n16)*72 + 32*h + 8*g);
      #pragma unroll
      for (int nt = 0; nt < 8; nt++){
        half8 bf = *(const half8*)(Kt + (16*nt + n16)*72 + 32*h + 8*g);
        acc[0][nt] = __builtin_amdgcn_mfma_f32_16x16x32_f16(pa[0], bf, acc[0][nt], 0,0,0);
        acc[1][nt] = __builtin_amdgcn_mfma_f32_16x16x32_f16(pa[1], bf, acc[1][nt], 0,0,0);
      }
    }
    __syncthreads();   // protect Kb/Kt/psw before next staging
  }

  // ---- epilogue: fp16 partial store ([q][dim] contiguous per chunk) ----
  f16* pb = part + (size_t)bid*(QTILE*DD) + (32*w)*DD;
  #pragma unroll
  for (int p = 0; p < 2; p++){
    #pragma unroll
    for (int nt = 0; nt < 8; nt++){
      #pragma unroll
      for (int r = 0; r < 4; r++){
        pb[(size_t)(16*p + 4*g + r)*DD + 16*nt + n16] = (f16)acc[p][nt][r];
      }
    }
  }
}

// ================= k_reduce: att = sum of fp16 partials (reversed-prefix base) ================
__global__ __launch_bounds__(256) void k_reduce(
    const f16* __restrict__ part, float* __restrict__ att)
{
  int bid = blockIdx.x;            // BB * 32 * 8 blocks
  int rg = bid & 7;
  int qt = (bid >> 3) & 31;
  int b  = bid >> 8;
  int nc = (qt + 4) >> 2;          // chunks for this q-tile
  int base = 0;                    // LPT order: chunks for qt sit after all larger qt's chunks
  #pragma unroll 1
  for (int j = NQT3-1; j > qt; j--) base += (j + 4) >> 2;
  int tid = threadIdx.x;
  size_t off = (size_t)rg*(16*DD) + tid*8;
  const f16* src = part + ((size_t)b*NCHUNK + base)*(QTILE*DD) + off;
  float a[8];
  {
    half8 v = *(const half8*)(src);
    #pragma unroll
    for (int u = 0; u < 8; u++) a[u] = (float)v[u];
  }
  for (int c = 1; c < nc; c++){
    half8 v = *(const half8*)(src + (size_t)c*(QTILE*DD));
    #pragma unroll
    for (int u = 0; u < 8; u++) a[u] += (float)v[u];
  }
  float* dst = att + ((size_t)b*TT + (size_t)qt*QTILE)*DD + off;
  f32x4 o0 = {a[0],a[1],a[2],a[3]}, o1 = {a[4],a[5],a[6],a[7]};
  *(f32x4*)(dst) = o0;
  *(f32x4*)(dst + 4) = o1;
}

// ================= k_comb: ki = proj(mf + att@Wo + bo); vsum += w*ki; retract =================
__global__ __launch_bounds__(256) void k_comb(
    const float* __restrict__ z, const float* __restrict__ Wo, const float* __restrict__ bo,
    const float* __restrict__ mf, const float* __restrict__ att,
    const float* __restrict__ zin, float* __restrict__ zout,
    float* __restrict__ vsum, float* __restrict__ out,
    float wsum, float cretr, int first, int last)
{
  __shared__ float Ws[DD*DD];
  __shared__ float As[32*DD];
  int tid = threadIdx.x;
  int r0 = blockIdx.x * 32;
  #pragma unroll
  for (int it = 0; it < 16; it++){
    int idx = tid + it*256;
    *(f32x4*)(Ws + idx*4) = *(const f32x4*)(Wo + (size_t)idx*4);
  }
  #pragma unroll
  for (int it = 0; it < 4; it++){
    int idx = tid + it*256;
    *(f32x4*)(As + idx*4) = *(const f32x4*)(att + (size_t)r0*DD + idx*4);
  }
  __syncthreads();
  int c = tid & 15, rr = tid >> 4;
  float kur0[8], kur1[8];
  #pragma unroll
  for (int u = 0; u < 8; u++){ float bv = bo[c*8+u]; kur0[u] = bv; kur1[u] = bv; }
  const float* ar0 = As + rr*DD;
  const float* ar1 = As + (rr+16)*DD;
  #pragma unroll 4
  for (int i = 0; i < DD; i++){
    f32x4 w0 = *(const f32x4*)(Ws + i*DD + c*8);
    f32x4 w1 = *(const f32x4*)(Ws + i*DD + c*8 + 4);
    float a0 = ar0[i], a1 = ar1[i];
    #pragma unroll
    for (int u = 0; u < 4; u++){
      kur0[u]   = fmaf(a0, w0[u], kur0[u]);   kur1[u]   = fmaf(a1, w0[u], kur1[u]);
      kur0[4+u] = fmaf(a0, w1[u], kur0[4+u]); kur1[4+u] = fmaf(a1, w1[u], kur1[4+u]);
    }
  }
  size_t o0 = (size_t)(r0+rr)*DD + c*8;
  size_t o1 = (size_t)(r0+rr+16)*DD + c*8;
  float tot0[8], tot1[8], zi0[8], zi1[8];
  {
    f32x4 m0a = *(const f32x4*)(mf + o0), m0b = *(const f32x4*)(mf + o0 + 4);
    f32x4 m1a = *(const f32x4*)(mf + o1), m1b = *(const f32x4*)(mf + o1 + 4);
    f32x4 z0a = *(const f32x4*)(zin + o0), z0b = *(const f32x4*)(zin + o0 + 4);
    f32x4 z1a = *(const f32x4*)(zin + o1), z1b = *(const f32x4*)(zin + o1 + 4);
    #pragma unroll
    for (int u = 0; u < 4; u++){
      tot0[u] = m0a[u] + kur0[u]; tot0[4+u] = m0b[u] + kur0[4+u];
      tot1[u] = m1a[u] + kur1[u]; tot1[4+u] = m1b[u] + kur1[4+u];
      zi0[u] = z0a[u]; zi0[4+u] = z0b[u];
      zi1[u] = z1a[u]; zi1[4+u] = z1b[u];
    }
  }
  float p0 = 0.f, p1 = 0.f;
  #pragma unroll
  for (int u = 0; u < 8; u++){ p0 = fmaf(tot0[u], zi0[u], p0); p1 = fmaf(tot1[u], zi1[u], p1); }
  #pragma unroll
  for (int m = 1; m < 16; m <<= 1){ p0 += __shfl_xor(p0, m, 16); p1 += __shfl_xor(p1, m, 16); }
  float ki0[8], ki1[8], vs0[8], vs1[8];
  #pragma unroll
  for (int u = 0; u < 8; u++){
    ki0[u] = tot0[u] - p0 * zi0[u];
    ki1[u] = tot1[u] - p1 * zi1[u];
  }
  if (first){
    #pragma unroll
    for (int u = 0; u < 8; u++){ vs0[u] = wsum*ki0[u]; vs1[u] = wsum*ki1[u]; }
  } else {
    f32x4 v0a = *(const f32x4*)(vsum + o0), v0b = *(const f32x4*)(vsum + o0 + 4);
    f32x4 v1a = *(const f32x4*)(vsum + o1), v1b = *(const f32x4*)(vsum + o1 + 4);
    #pragma unroll
    for (int u = 0; u < 4; u++){
      vs0[u] = fmaf(wsum, ki0[u], v0a[u]); vs0[4+u] = fmaf(wsum, ki0[4+u], v0b[u]);
      vs1[u] = fmaf(wsum, ki1[u], v1a[u]); vs1[4+u] = fmaf(wsum, ki1[4+u], v1b[u]);
    }
  }
  if (!last){
    f32x4 va = {vs0[0],vs0[1],vs0[2],vs0[3]}, vb = {vs0[4],vs0[5],vs0[6],vs0[7]};
    f32x4 vc = {vs1[0],vs1[1],vs1[2],vs1[3]}, vd = {vs1[4],vs1[5],vs1[6],vs1[7]};
    *(f32x4*)(vsum + o0) = va; *(f32x4*)(vsum + o0 + 4) = vb;
    *(f32x4*)(vsum + o1) = vc; *(f32x4*)(vsum + o1 + 4) = vd;
  }
  float nz0[8], nz1[8];
  {
    f32x4 z0a = *(const f32x4*)(z + o0), z0b = *(const f32x4*)(z + o0 + 4);
    f32x4 z1a = *(const f32x4*)(z + o1), z1b = *(const f32x4*)(z + o1 + 4);
    #pragma unroll
    for (int u = 0; u < 4; u++){
      float d0a = last ? vs0[u]*(1.f/6.f)   : cretr*ki0[u];
      float d0b = last ? vs0[4+u]*(1.f/6.f) : cretr*ki0[4+u];
      float d1a = last ? vs1[u]*(1.f/6.f)   : cretr*ki1[u];
      float d1b = last ? vs1[4+u]*(1.f/6.f) : cretr*ki1[4+u];
      nz0[u] = z0a[u] + d0a; nz0[4+u] = z0b[u] + d0b;
      nz1[u] = z1a[u] + d1a; nz1[4+u] = z1b[u] + d1b;
    }
  }
  float n0 = 0.f, n1 = 0.f;
  #pragma unroll
  for (int u = 0; u < 8; u++){ n0 = fmaf(nz0[u], nz0[u], n0); n1 = fmaf(nz1[u], nz1[u], n1); }
  #pragma unroll
  for (int m = 1; m < 16; m <<= 1){ n0 += __shfl_xor(n0, m, 16); n1 += __shfl_xor(n1, m, 16); }
  float i0 = 1.f / fmaxf(sqrtf(n0), 1e-8f);
  float i1 = 1.f / fmaxf(sqrtf(n1), 1e-8f);
  float* dst = last ? out : zout;
  f32x4 ra = {nz0[0]*i0, nz0[1]*i0, nz0[2]*i0, nz0[3]*i0};
  f32x4 rb = {nz0[4]*i0, nz0[5]*i0, nz0[6]*i0, nz0[7]*i0};
  f32x4 rc = {nz1[0]*i1, nz1[1]*i1, nz1[2]*i1, nz1[3]*i1};
  f32x4 rd = {nz1[4]*i1, nz1[5]*i1, nz1[6]*i1, nz1[7]*i1};
  *(f32x4*)(dst + o0) = ra; *(f32x4*)(dst + o0 + 4) = rb;
  *(f32x4*)(dst + o1) = rc; *(f32x4*)(dst + o1 + 4) = rd;
}

extern "C" void kernel_launch(void* const* d_in, const int* in_sizes, int n_in,
                              void* d_out, int out_size, void* d_ws, size_t ws_size,
                              hipStream_t stream) {
  const float* z  = (const float*)d_in[0];
  const float* ck = (const float*)d_in[1];
  const float* cb = (const float*)d_in[2];
  const float* Wq = (const float*)d_in[3];
  const float* bq = (const float*)d_in[4];
  const float* Wk = (const float*)d_in[5];
  const float* bk = (const float*)d_in[6];
  const float* Wo = (const float*)d_in[7];
  const float* bo = (const float*)d_in[8];
  float* out = (float*)d_out;

  float* mf   = (float*)d_ws;          // [B,T,D] f32
  float* zc   = mf   + NELT;
  float* att  = zc   + NELT;
  float* vsum = att  + NELT;
  f16*   khb  = (f16*)(vsum + NELT);   // fp16 [B,T,D]
  f16*   khT  = khb  + NELT;           // fp16 [B,D,T]
  f16*   qhb  = khT  + NELT;           // fp16 [B,T,D]
  f16*   part = qhb  + NELT;           // [BB*NCHUNK][128][128] fp16 partials (~9.4 MB)

  k_prep<<<768, 256, 0, stream>>>(z, Wk, bk, ck, cb, khb, khT, mf);

  const float wv[4] = {1.f, 2.f, 2.f, 1.f};
  const float cv[4] = {0.5f, 0.5f, 1.f, 0.f};
  for (int st = 0; st < 4; st++){
    const float* zcur = (st == 0) ? z : zc;
    k_q     <<<NROW/32, 256, 0, stream>>>(zcur, Wq, bq, qhb);
    k_attn13<<<BB*NCHUNK, 256, 0, stream>>>(qhb, khb, khT, part);
    k_reduce<<<BB*NQT3*8, 256, 0, stream>>>(part, att);
    k_comb  <<<NROW/32, 256, 0, stream>>>(z, Wo, bo, mf, att, zcur, zc, vsum, out,
                                          wv[st], cv[st], st == 0, st == 3);
  }
}

// Round 19
// 294.978 us; speedup vs baseline: 1.1165x; 1.0116x over previous
//
#include <hip/hip_runtime.h>
#include <hip/hip_bf16.h>

#define BB 2
#define TT 4096
#define DD 128
#define KK 256
#define NROW (BB*TT)    // 8192 rows
#define NELT (NROW*DD)  // 1048576 elements per [B,T,D] buffer

typedef _Float16 f16;
typedef __attribute__((ext_vector_type(8))) f16 half8;
typedef __attribute__((ext_vector_type(2))) __fp16 fp16x2;
typedef __attribute__((ext_vector_type(4))) float f32x4;
typedef __attribute__((ext_vector_type(2))) int i32x2;

__device__ __forceinline__ int pack2(float a, float b){
  fp16x2 h = __builtin_amdgcn_cvt_pkrtz(a, b);
  return __builtin_bit_cast(int, h);
}

// ---- shared device helper: 32-row fp32 matvec + normalize -> fp16 rows (optionally +transpose)
__device__ __forceinline__ void proj_norm_rows(
    int tid, int r0,
    const float* __restrict__ src, const float* __restrict__ W, const float* __restrict__ bias,
    f16* __restrict__ dst, f16* __restrict__ dstT)
{
  __shared__ float Ws[DD*DD];
  __shared__ float zs[32*DD];
  #pragma unroll
  for (int it = 0; it < 16; it++){
    int idx = tid + it*256;
    *(f32x4*)(Ws + idx*4) = *(const f32x4*)(W + (size_t)idx*4);
  }
  #pragma unroll
  for (int it = 0; it < 4; it++){
    int idx = tid + it*256;
    *(f32x4*)(zs + idx*4) = *(const f32x4*)(src + (size_t)r0*DD + idx*4);
  }
  __syncthreads();
  int c = tid & 15, rr = tid >> 4;
  float acc0[8], acc1[8];
  #pragma unroll
  for (int u = 0; u < 8; u++){ float bv = bias[c*8+u]; acc0[u] = bv; acc1[u] = bv; }
  const float* zr0 = zs + rr*DD;
  const float* zr1 = zs + (rr+16)*DD;
  #pragma unroll 4
  for (int i = 0; i < DD; i++){
    f32x4 w0 = *(const f32x4*)(Ws + i*DD + c*8);
    f32x4 w1 = *(const f32x4*)(Ws + i*DD + c*8 + 4);
    float a0 = zr0[i], a1 = zr1[i];
    #pragma unroll
    for (int u = 0; u < 4; u++){
      acc0[u]   = fmaf(a0, w0[u], acc0[u]);   acc1[u]   = fmaf(a1, w0[u], acc1[u]);
      acc0[4+u] = fmaf(a0, w1[u], acc0[4+u]); acc1[4+u] = fmaf(a1, w1[u], acc1[4+u]);
    }
  }
  float s0 = 0.f, s1 = 0.f;
  #pragma unroll
  for (int u = 0; u < 8; u++){ s0 = fmaf(acc0[u], acc0[u], s0); s1 = fmaf(acc1[u], acc1[u], s1); }
  #pragma unroll
  for (int m = 1; m < 16; m <<= 1){ s0 += __shfl_xor(s0, m, 16); s1 += __shfl_xor(s1, m, 16); }
  float inv0 = 1.f / fmaxf(sqrtf(s0), 1e-8f);
  float inv1 = 1.f / fmaxf(sqrtf(s1), 1e-8f);
  half8 h0, h1;
  #pragma unroll
  for (int u = 0; u < 8; u++){ h0[u] = (f16)(acc0[u]*inv0); h1[u] = (f16)(acc1[u]*inv1); }
  int row0 = r0 + rr, row1 = row0 + 16;
  *(half8*)(dst + (size_t)row0*DD + c*8) = h0;
  *(half8*)(dst + (size_t)row1*DD + c*8) = h1;
  if (dstT){
    int b = row0 >> 12, t0 = row0 & 4095, t1 = row1 & 4095;
    #pragma unroll
    for (int u = 0; u < 8; u++){
      dstT[((size_t)b*DD + c*8 + u)*TT + t0] = h0[u];
      dstT[((size_t)b*DD + c*8 + u)*TT + t1] = h1[u];
    }
  }
}

// ======== k_prep: merged one-shot. blocks 0..511: conv; 512..767: k-proj; 768..1023: q0-proj ==
__global__ __launch_bounds__(256) void k_prep(
    const float* __restrict__ z, const float* __restrict__ Wk, const float* __restrict__ bk,
    const float* __restrict__ ck, const float* __restrict__ cb,
    const float* __restrict__ Wq, const float* __restrict__ bq,
    f16* __restrict__ khb, f16* __restrict__ khT, f16* __restrict__ qhb,
    float* __restrict__ mf)
{
  int tid = threadIdx.x;
  if (blockIdx.x < 512){
    // ---- conv: register sliding window (heaviest; launched first for LPT) ----
    int bid = blockIdx.x;
    int d = tid & 127, tg = tid >> 7;
    int b = bid >> 8;
    int tbase = ((bid & 255) << 4) + tg*8;
    const float* zb = z + (size_t)b*TT*DD;
    float acc[8];
    #pragma unroll
    for (int j = 0; j < 8; j++) acc[j] = 0.f;
    float ckq[8];
    #pragma unroll
    for (int u = 0; u < 8; u++) ckq[u] = 0.f;
    int sstart = tbase - (KK-1);
    for (int ch = 0; ch < 33; ch++){
      #pragma unroll
      for (int u = 0; u < 8; u++){
        int base = ch*8 + u;
        int s = sstart + base;
        float zv = ((unsigned)s < (unsigned)TT && base < 263) ? zb[(size_t)s*DD + d] : 0.f;
        ckq[u] = (base < KK) ? ck[(size_t)base*DD + d] : 0.f;
        #pragma unroll
        for (int j = 0; j < 8; j++) acc[j] = fmaf(ckq[(u-j)&7], zv, acc[j]);
      }
    }
    float cbv = cb[d];
    #pragma unroll
    for (int j = 0; j < 8; j++)
      mf[((size_t)b*TT + tbase + j)*DD + d] = acc[j] + cbv;
  } else if (blockIdx.x < 768){
    proj_norm_rows(tid, (blockIdx.x - 512) * 32, z, Wk, bk, khb, khT);
  } else {
    proj_norm_rows(tid, (blockIdx.x - 768) * 32, z, Wq, bq, qhb, nullptr);
  }
}

// ================= k_q: q_hat = normalize(zcur@Wq+bq) -> fp16 (stages 1..3) =================
__global__ __launch_bounds__(256) void k_q(
    const float* __restrict__ zcur, const float* __restrict__ Wq, const float* __restrict__ bq,
    f16* __restrict__ qhb)
{
  proj_norm_rows(threadIdx.x, blockIdx.x * 32, zcur, Wq, bq, qhb, nullptr);
}

// ====== MFMA attention v13: chunks of 8 key-tiles, LPT order (qt descending with bid) ==========
#define QTILE 128
#define NQT3 (TT/QTILE)     // 32 q-tiles per batch
#define NCHUNK 144          // sum_{qt=0}^{31} ceil((qt+1)/4)

__global__ __launch_bounds__(256,2) void k_attn13(
    const f16* __restrict__ qhb, const f16* __restrict__ khb,
    const f16* __restrict__ khT, f16* __restrict__ part)
{
  int bid = blockIdx.x;
  int b = bid / NCHUNK;
  int rem = bid - b*NCHUNK;
  int qt = 0, chunk = 0;
  // LPT: large qt (8-iter blocks) first
  #pragma unroll 1
  for (int j = NQT3-1; j >= 0; j--){
    int nch = (j + 4) >> 2;     // ceil((j+1)/4)
    if (rem < nch){ qt = j; chunk = rem; break; }
    rem -= nch;
  }
  int kt0 = chunk * 8;
  int kt1 = min(kt0 + 7, 2*qt + 1);
  int t0 = qt * QTILE;

  __shared__ __align__(16) f16 Kb[64*136];     // [key][dim],  stride 136 (17408 B)
  __shared__ __align__(16) f16 Kt[128*72];     // [dim][key],  stride 72  (18432 B)
  __shared__ __align__(16) f16 Ps[4][32*72];   // per-wave P fp16, [q][key], stride 72 (18432 B)

  int tid  = threadIdx.x;
  int w    = tid >> 6;
  int lane = tid & 63;
  int n16  = lane & 15;
  int g    = lane >> 4;

  const f16* qg  = qhb + (size_t)b*TT*DD;
  const f16* kg  = khb + (size_t)b*TT*DD;
  const f16* ktg = khT + (size_t)b*DD*TT;

  int sb_r  = tid >> 4, sb_c = (tid & 15)*8;   // Kb staging base
  int st_r  = tid >> 3, st_c = (tid & 7)*8;    // Kt staging base

  half8 qa[2][4];   // Q rows; used as MFMA B-operand (A/B lane maps identical for 16x16x32 f16)
  #pragma unroll
  for (int p = 0; p < 2; p++){
    const f16* qrow = qg + (size_t)(t0 + 32*w + 16*p + n16)*DD + g*8;
    #pragma unroll
    for (int c = 0; c < 4; c++) qa[p][c] = *(const half8*)(qrow + 32*c);
  }
  f32x4 acc[2][8];
  #pragma unroll
  for (int p = 0; p < 2; p++)
    #pragma unroll
    for (int i = 0; i < 8; i++) acc[p][i] = (f32x4){0.f,0.f,0.f,0.f};

  f16* psw = &Ps[w][0];

  // ---- register prefetch of first K tile ----
  half8 sKb[4], sKt[4];
  {
    int s0 = kt0 * 64;
    #pragma unroll
    for (int it = 0; it < 4; it++)
      sKb[it] = *(const half8*)(kg + (size_t)(s0 + sb_r + it*16)*DD + sb_c);
    #pragma unroll
    for (int it = 0; it < 4; it++)
      sKt[it] = *(const half8*)(ktg + (size_t)(st_r + it*32)*TT + s0 + st_c);
  }

  for (int kt = kt0; kt <= kt1; kt++){
    #pragma unroll
    for (int it = 0; it < 4; it++)
      *(half8*)(Kb + (sb_r + it*16)*136 + sb_c) = sKb[it];
    #pragma unroll
    for (int it = 0; it < 4; it++)
      *(half8*)(Kt + (st_r + it*32)*72 + st_c) = sKt[it];
    __syncthreads();

    if (kt < kt1){
      int s0n = (kt+1) * 64;
      #pragma unroll
      for (int it = 0; it < 4; it++)
        sKb[it] = *(const half8*)(kg + (size_t)(s0n + sb_r + it*16)*DD + sb_c);
      #pragma unroll
      for (int it = 0; it < 4; it++)
        sKt[it] = *(const half8*)(ktg + (size_t)(st_r + it*32)*TT + s0n + st_c);
    }

    int s0 = kt * 64;
    // ---- QK^T transposed: A = K rows (Kb), B = Q regs -> S^T[m=key][n=query] ----
    f32x4 s_acc[2][4];
    #pragma unroll
    for (int p = 0; p < 2; p++)
      #pragma unroll
      for (int n = 0; n < 4; n++) s_acc[p][n] = (f32x4){0.f,0.f,0.f,0.f};
    #pragma unroll
    for (int c = 0; c < 4; c++){
      #pragma unroll
      for (int n = 0; n < 4; n++){
        half8 af = *(const half8*)(Kb + (16*n + n16)*136 + 32*c + g*8);
        s_acc[0][n] = __builtin_amdgcn_mfma_f32_16x16x32_f16(af, qa[0][c], s_acc[0][n], 0,0,0);
        s_acc[1][n] = __builtin_amdgcn_mfma_f32_16x16x32_f16(af, qa[1][c], s_acc[1][n], 0,0,0);
      }
    }
    // ---- sin + mask; lane holds q=n16, keys 16n+4g+r -> pack 4 keys -> ONE b64 write ----
    #pragma unroll
    for (int p = 0; p < 2; p++){
      int qrow = t0 + 32*w + 16*p + n16;
      #pragma unroll
      for (int n = 0; n < 4; n++){
        int keyr = s0 + 16*n + 4*g;
        float v0 = (keyr     <= qrow) ? __sinf(s_acc[p][n][0]) : 0.f;
        float v1 = (keyr + 1 <= qrow) ? __sinf(s_acc[p][n][1]) : 0.f;
        float v2 = (keyr + 2 <= qrow) ? __sinf(s_acc[p][n][2]) : 0.f;
        float v3 = (keyr + 3 <= qrow) ? __sinf(s_acc[p][n][3]) : 0.f;
        i32x2 pw = { pack2(v0, v1), pack2(v2, v3) };
        *(i32x2*)(psw + (16*p + n16)*72 + 16*n + 4*g) = pw;
      }
    }
    // intra-wave RAW on psw ordered by lgkmcnt (per-wave buffer, no barrier)

    // ---- PV: A = P rows (Ps[q][key] b128), B = Kt rows -> O[q][dim] ----
    #pragma unroll
    for (int h = 0; h < 2; h++){
      half8 pa[2];
      #pragma unroll
      for (int p = 0; p < 2; p++)
        pa[p] = *(const half8*)(psw + (16*p + n16)*72 + 32*h + 8*g);
      #pragma unroll
      for (int nt = 0; nt < 8; nt++){
        half8 bf = *(const half8*)(Kt + (16*nt + n16)*72 + 32*h + 8*g);
        acc[0][nt] = __builtin_amdgcn_mfma_f32_16x16x32_f16(pa[0], bf, acc[0][nt], 0,0,0);
        acc[1][nt] = __builtin_amdgcn_mfma_f32_16x16x32_f16(pa[1], bf, acc[1][nt], 0,0,0);
      }
    }
    __syncthreads();   // protect Kb/Kt/psw before next staging
  }

  // ---- epilogue: fp16 partial store ([q][dim] contiguous per chunk) ----
  f16* pb = part + (size_t)bid*(QTILE*DD) + (32*w)*DD;
  #pragma unroll
  for (int p = 0; p < 2; p++){
    #pragma unroll
    for (int nt = 0; nt < 8; nt++){
      #pragma unroll
      for (int r = 0; r < 4; r++){
        pb[(size_t)(16*p + 4*g + r)*DD + 16*nt + n16] = (f16)acc[p][nt][r];
      }
    }
  }
}

// ================= k_reduce: att = sum of fp16 partials (reversed-prefix base) ================
__global__ __launch_bounds__(256) void k_reduce(
    const f16* __restrict__ part, float* __restrict__ att)
{
  int bid = blockIdx.x;            // BB * 32 * 8 blocks
  int rg = bid & 7;
  int qt = (bid >> 3) & 31;
  int b  = bid >> 8;
  int nc = (qt + 4) >> 2;          // chunks for this q-tile
  int base = 0;                    // LPT order: chunks for qt sit after all larger qt's chunks
  #pragma unroll 1
  for (int j = NQT3-1; j > qt; j--) base += (j + 4) >> 2;
  int tid = threadIdx.x;
  size_t off = (size_t)rg*(16*DD) + tid*8;
  const f16* src = part + ((size_t)b*NCHUNK + base)*(QTILE*DD) + off;
  float a[8];
  {
    half8 v = *(const half8*)(src);
    #pragma unroll
    for (int u = 0; u < 8; u++) a[u] = (float)v[u];
  }
  for (int c = 1; c < nc; c++){
    half8 v = *(const half8*)(src + (size_t)c*(QTILE*DD));
    #pragma unroll
    for (int u = 0; u < 8; u++) a[u] += (float)v[u];
  }
  float* dst = att + ((size_t)b*TT + (size_t)qt*QTILE)*DD + off;
  f32x4 o0 = {a[0],a[1],a[2],a[3]}, o1 = {a[4],a[5],a[6],a[7]};
  *(f32x4*)(dst) = o0;
  *(f32x4*)(dst + 4) = o1;
}

// ================= k_comb: ki = proj(mf + att@Wo + bo); vsum += w*ki; retract =================
__global__ __launch_bounds__(256) void k_comb(
    const float* __restrict__ z, const float* __restrict__ Wo, const float* __restrict__ bo,
    const float* __restrict__ mf, const float* __restrict__ att,
    const float* __restrict__ zin, float* __restrict__ zout,
    float* __restrict__ vsum, float* __restrict__ out,
    float wsum, float cretr, int first, int last)
{
  __shared__ float Ws[DD*DD];
  __shared__ float As[32*DD];
  int tid = threadIdx.x;
  int r0 = blockIdx.x * 32;
  #pragma unroll
  for (int it = 0; it < 16; it++){
    int idx = tid + it*256;
    *(f32x4*)(Ws + idx*4) = *(const f32x4*)(Wo + (size_t)idx*4);
  }
  #pragma unroll
  for (int it = 0; it < 4; it++){
    int idx = tid + it*256;
    *(f32x4*)(As + idx*4) = *(const f32x4*)(att + (size_t)r0*DD + idx*4);
  }
  __syncthreads();
  int c = tid & 15, rr = tid >> 4;
  float kur0[8], kur1[8];
  #pragma unroll
  for (int u = 0; u < 8; u++){ float bv = bo[c*8+u]; kur0[u] = bv; kur1[u] = bv; }
  const float* ar0 = As + rr*DD;
  const float* ar1 = As + (rr+16)*DD;
  #pragma unroll 4
  for (int i = 0; i < DD; i++){
    f32x4 w0 = *(const f32x4*)(Ws + i*DD + c*8);
    f32x4 w1 = *(const f32x4*)(Ws + i*DD + c*8 + 4);
    float a0 = ar0[i], a1 = ar1[i];
    #pragma unroll
    for (int u = 0; u < 4; u++){
      kur0[u]   = fmaf(a0, w0[u], kur0[u]);   kur1[u]   = fmaf(a1, w0[u], kur1[u]);
      kur0[4+u] = fmaf(a0, w1[u], kur0[4+u]); kur1[4+u] = fmaf(a1, w1[u], kur1[4+u]);
    }
  }
  size_t o0 = (size_t)(r0+rr)*DD + c*8;
  size_t o1 = (size_t)(r0+rr+16)*DD + c*8;
  float tot0[8], tot1[8], zi0[8], zi1[8];
  {
    f32x4 m0a = *(const f32x4*)(mf + o0), m0b = *(const f32x4*)(mf + o0 + 4);
    f32x4 m1a = *(const f32x4*)(mf + o1), m1b = *(const f32x4*)(mf + o1 + 4);
    f32x4 z0a = *(const f32x4*)(zin + o0), z0b = *(const f32x4*)(zin + o0 + 4);
    f32x4 z1a = *(const f32x4*)(zin + o1), z1b = *(const f32x4*)(zin + o1 + 4);
    #pragma unroll
    for (int u = 0; u < 4; u++){
      tot0[u] = m0a[u] + kur0[u]; tot0[4+u] = m0b[u] + kur0[4+u];
      tot1[u] = m1a[u] + kur1[u]; tot1[4+u] = m1b[u] + kur1[4+u];
      zi0[u] = z0a[u]; zi0[4+u] = z0b[u];
      zi1[u] = z1a[u]; zi1[4+u] = z1b[u];
    }
  }
  float p0 = 0.f, p1 = 0.f;
  #pragma unroll
  for (int u = 0; u < 8; u++){ p0 = fmaf(tot0[u], zi0[u], p0); p1 = fmaf(tot1[u], zi1[u], p1); }
  #pragma unroll
  for (int m = 1; m < 16; m <<= 1){ p0 += __shfl_xor(p0, m, 16); p1 += __shfl_xor(p1, m, 16); }
  float ki0[8], ki1[8], vs0[8], vs1[8];
  #pragma unroll
  for (int u = 0; u < 8; u++){
    ki0[u] = tot0[u] - p0 * zi0[u];
    ki1[u] = tot1[u] - p1 * zi1[u];
  }
  if (first){
    #pragma unroll
    for (int u = 0; u < 8; u++){ vs0[u] = wsum*ki0[u]; vs1[u] = wsum*ki1[u]; }
  } else {
    f32x4 v0a = *(const f32x4*)(vsum + o0), v0b = *(const f32x4*)(vsum + o0 + 4);
    f32x4 v1a = *(const f32x4*)(vsum + o1), v1b = *(const f32x4*)(vsum + o1 + 4);
    #pragma unroll
    for (int u = 0; u < 4; u++){
      vs0[u] = fmaf(wsum, ki0[u], v0a[u]); vs0[4+u] = fmaf(wsum, ki0[4+u], v0b[u]);
      vs1[u] = fmaf(wsum, ki1[u], v1a[u]); vs1[4+u] = fmaf(wsum, ki1[4+u], v1b[u]);
    }
  }
  if (!last){
    f32x4 va = {vs0[0],vs0[1],vs0[2],vs0[3]}, vb = {vs0[4],vs0[5],vs0[6],vs0[7]};
    f32x4 vc = {vs1[0],vs1[1],vs1[2],vs1[3]}, vd = {vs1[4],vs1[5],vs1[6],vs1[7]};
    *(f32x4*)(vsum + o0) = va; *(f32x4*)(vsum + o0 + 4) = vb;
    *(f32x4*)(vsum + o1) = vc; *(f32x4*)(vsum + o1 + 4) = vd;
  }
  float nz0[8], nz1[8];
  {
    f32x4 z0a = *(const f32x4*)(z + o0), z0b = *(const f32x4*)(z + o0 + 4);
    f32x4 z1a = *(const f32x4*)(z + o1), z1b = *(const f32x4*)(z + o1 + 4);
    #pragma unroll
    for (int u = 0; u < 4; u++){
      float d0a = last ? vs0[u]*(1.f/6.f)   : cretr*ki0[u];
      float d0b = last ? vs0[4+u]*(1.f/6.f) : cretr*ki0[4+u];
      float d1a = last ? vs1[u]*(1.f/6.f)   : cretr*ki1[u];
      float d1b = last ? vs1[4+u]*(1.f/6.f) : cretr*ki1[4+u];
      nz0[u] = z0a[u] + d0a; nz0[4+u] = z0b[u] + d0b;
      nz1[u] = z1a[u] + d1a; nz1[4+u] = z1b[u] + d1b;
    }
  }
  float n0 = 0.f, n1 = 0.f;
  #pragma unroll
  for (int u = 0; u < 8; u++){ n0 = fmaf(nz0[u], nz0[u], n0); n1 = fmaf(nz1[u], nz1[u], n1); }
  #pragma unroll
  for (int m = 1; m < 16; m <<= 1){ n0 += __shfl_xor(n0, m, 16); n1 += __shfl_xor(n1, m, 16); }
  float i0 = 1.f / fmaxf(sqrtf(n0), 1e-8f);
  float i1 = 1.f / fmaxf(sqrtf(n1), 1e-8f);
  float* dst = last ? out : zout;
  f32x4 ra = {nz0[0]*i0, nz0[1]*i0, nz0[2]*i0, nz0[3]*i0};
  f32x4 rb = {nz0[4]*i0, nz0[5]*i0, nz0[6]*i0, nz0[7]*i0};
  f32x4 rc = {nz1[0]*i1, nz1[1]*i1, nz1[2]*i1, nz1[3]*i1};
  f32x4 rd = {nz1[4]*i1, nz1[5]*i1, nz1[6]*i1, nz1[7]*i1};
  *(f32x4*)(dst + o0) = ra; *(f32x4*)(dst + o0 + 4) = rb;
  *(f32x4*)(dst + o1) = rc; *(f32x4*)(dst + o1 + 4) = rd;
}

extern "C" void kernel_launch(void* const* d_in, const int* in_sizes, int n_in,
                              void* d_out, int out_size, void* d_ws, size_t ws_size,
                              hipStream_t stream) {
  const float* z  = (const float*)d_in[0];
  const float* ck = (const float*)d_in[1];
  const float* cb = (const float*)d_in[2];
  const float* Wq = (const float*)d_in[3];
  const float* bq = (const float*)d_in[4];
  const float* Wk = (const float*)d_in[5];
  const float* bk = (const float*)d_in[6];
  const float* Wo = (const float*)d_in[7];
  const float* bo = (const float*)d_in[8];
  float* out = (float*)d_out;

  float* mf   = (float*)d_ws;          // [B,T,D] f32
  float* zc   = mf   + NELT;
  float* att  = zc   + NELT;
  float* vsum = att  + NELT;
  f16*   khb  = (f16*)(vsum + NELT);   // fp16 [B,T,D]
  f16*   khT  = khb  + NELT;           // fp16 [B,D,T]
  f16*   qhb  = khT  + NELT;           // fp16 [B,T,D]
  f16*   part = qhb  + NELT;           // [BB*NCHUNK][128][128] fp16 partials (~9.4 MB)

  k_prep<<<1024, 256, 0, stream>>>(z, Wk, bk, ck, cb, Wq, bq, khb, khT, qhb, mf);

  const float wv[4] = {1.f, 2.f, 2.f, 1.f};
  const float cv[4] = {0.5f, 0.5f, 1.f, 0.f};
  for (int st = 0; st < 4; st++){
    const float* zcur = (st == 0) ? z : zc;
    if (st > 0)
      k_q   <<<NROW/32, 256, 0, stream>>>(zcur, Wq, bq, qhb);
    k_attn13<<<BB*NCHUNK, 256, 0, stream>>>(qhb, khb, khT, part);
    k_reduce<<<BB*NQT3*8, 256, 0, stream>>>(part, att);
    k_comb  <<<NROW/32, 256, 0, stream>>>(z, Wo, bo, mf, att, zcur, zc, vsum, out,
                                          wv[st], cv[st], st == 0, st == 3);
  }
}

// Round 20
// 292.473 us; speedup vs baseline: 1.1260x; 1.0086x over previous
//
#include <hip/hip_runtime.h>
#include <hip/hip_bf16.h>

#define BB 2
#define TT 4096
#define DD 128
#define KK 256
#define NROW (BB*TT)    // 8192 rows
#define NELT (NROW*DD)  // 1048576 elements per [B,T,D] buffer

typedef _Float16 f16;
typedef __attribute__((ext_vector_type(8))) f16 half8;
typedef __attribute__((ext_vector_type(2))) __fp16 fp16x2;
typedef __attribute__((ext_vector_type(4))) float f32x4;
typedef __attribute__((ext_vector_type(2))) int i32x2;

__device__ __forceinline__ int pack2(float a, float b){
  fp16x2 h = __builtin_amdgcn_cvt_pkrtz(a, b);
  return __builtin_bit_cast(int, h);
}

// ---- stage a 128x128 f32 weight matrix into LDS as fp16 (32 KB) ----
__device__ __forceinline__ void stage_w_f16(int tid, const float* __restrict__ W, f16* Wh){
  #pragma unroll
  for (int it = 0; it < 8; it++){
    int idx = tid + it*256;               // 2048 half8 chunks
    f32x4 a = *(const f32x4*)(W + (size_t)idx*8);
    f32x4 b = *(const f32x4*)(W + (size_t)idx*8 + 4);
    half8 h;
    #pragma unroll
    for (int u = 0; u < 4; u++){ h[u] = (f16)a[u]; h[4+u] = (f16)b[u]; }
    *(half8*)(Wh + (size_t)idx*8) = h;
  }
}

// ---- shared helper: 32-row fp32 matvec (fp16 W in LDS) + normalize -> fp16 rows (+transpose)
__device__ __forceinline__ void proj_norm_rows(
    int tid, int r0,
    const float* __restrict__ src, const float* __restrict__ W, const float* __restrict__ bias,
    f16* __restrict__ dst, f16* __restrict__ dstT)
{
  __shared__ f16 Wh[DD*DD];      // 32 KB
  __shared__ float zs[32*DD];    // 16 KB
  stage_w_f16(tid, W, Wh);
  #pragma unroll
  for (int it = 0; it < 4; it++){
    int idx = tid + it*256;
    *(f32x4*)(zs + idx*4) = *(const f32x4*)(src + (size_t)r0*DD + idx*4);
  }
  __syncthreads();
  int c = tid & 15, rr = tid >> 4;
  float acc0[8], acc1[8];
  #pragma unroll
  for (int u = 0; u < 8; u++){ float bv = bias[c*8+u]; acc0[u] = bv; acc1[u] = bv; }
  const float* zr0 = zs + rr*DD;
  const float* zr1 = zs + (rr+16)*DD;
  #pragma unroll 4
  for (int i = 0; i < DD; i++){
    half8 wv = *(const half8*)(Wh + i*DD + c*8);
    float a0 = zr0[i], a1 = zr1[i];
    #pragma unroll
    for (int u = 0; u < 8; u++){
      float w = (float)wv[u];
      acc0[u] = fmaf(a0, w, acc0[u]);
      acc1[u] = fmaf(a1, w, acc1[u]);
    }
  }
  float s0 = 0.f, s1 = 0.f;
  #pragma unroll
  for (int u = 0; u < 8; u++){ s0 = fmaf(acc0[u], acc0[u], s0); s1 = fmaf(acc1[u], acc1[u], s1); }
  #pragma unroll
  for (int m = 1; m < 16; m <<= 1){ s0 += __shfl_xor(s0, m, 16); s1 += __shfl_xor(s1, m, 16); }
  float inv0 = 1.f / fmaxf(sqrtf(s0), 1e-8f);
  float inv1 = 1.f / fmaxf(sqrtf(s1), 1e-8f);
  half8 h0, h1;
  #pragma unroll
  for (int u = 0; u < 8; u++){ h0[u] = (f16)(acc0[u]*inv0); h1[u] = (f16)(acc1[u]*inv1); }
  int row0 = r0 + rr, row1 = row0 + 16;
  *(half8*)(dst + (size_t)row0*DD + c*8) = h0;
  *(half8*)(dst + (size_t)row1*DD + c*8) = h1;
  if (dstT){
    int b = row0 >> 12, t0 = row0 & 4095, t1 = row1 & 4095;
    #pragma unroll
    for (int u = 0; u < 8; u++){
      dstT[((size_t)b*DD + c*8 + u)*TT + t0] = h0[u];
      dstT[((size_t)b*DD + c*8 + u)*TT + t1] = h1[u];
    }
  }
}

// ======== k_prep: merged one-shot. blocks 0..511: conv; 512..767: k-proj; 768..1023: q0-proj ==
__global__ __launch_bounds__(256) void k_prep(
    const float* __restrict__ z, const float* __restrict__ Wk, const float* __restrict__ bk,
    const float* __restrict__ ck, const float* __restrict__ cb,
    const float* __restrict__ Wq, const float* __restrict__ bq,
    f16* __restrict__ khb, f16* __restrict__ khT, f16* __restrict__ qhb,
    float* __restrict__ mf)
{
  int tid = threadIdx.x;
  if (blockIdx.x < 512){
    // ---- conv: register sliding window (heaviest; launched first for LPT) ----
    int bid = blockIdx.x;
    int d = tid & 127, tg = tid >> 7;
    int b = bid >> 8;
    int tbase = ((bid & 255) << 4) + tg*8;
    const float* zb = z + (size_t)b*TT*DD;
    float acc[8];
    #pragma unroll
    for (int j = 0; j < 8; j++) acc[j] = 0.f;
    float ckq[8];
    #pragma unroll
    for (int u = 0; u < 8; u++) ckq[u] = 0.f;
    int sstart = tbase - (KK-1);
    for (int ch = 0; ch < 33; ch++){
      #pragma unroll
      for (int u = 0; u < 8; u++){
        int base = ch*8 + u;
        int s = sstart + base;
        float zv = ((unsigned)s < (unsigned)TT && base < 263) ? zb[(size_t)s*DD + d] : 0.f;
        ckq[u] = (base < KK) ? ck[(size_t)base*DD + d] : 0.f;
        #pragma unroll
        for (int j = 0; j < 8; j++) acc[j] = fmaf(ckq[(u-j)&7], zv, acc[j]);
      }
    }
    float cbv = cb[d];
    #pragma unroll
    for (int j = 0; j < 8; j++)
      mf[((size_t)b*TT + tbase + j)*DD + d] = acc[j] + cbv;
  } else if (blockIdx.x < 768){
    proj_norm_rows(tid, (blockIdx.x - 512) * 32, z, Wk, bk, khb, khT);
  } else {
    proj_norm_rows(tid, (blockIdx.x - 768) * 32, z, Wq, bq, qhb, nullptr);
  }
}

// ================= k_q: q_hat = normalize(zcur@Wq+bq) -> fp16 (stages 1..3) =================
__global__ __launch_bounds__(256) void k_q(
    const float* __restrict__ zcur, const float* __restrict__ Wq, const float* __restrict__ bq,
    f16* __restrict__ qhb)
{
  proj_norm_rows(threadIdx.x, blockIdx.x * 32, zcur, Wq, bq, qhb, nullptr);
}

// ====== MFMA attention v13: chunks of 8 key-tiles, LPT order (qt descending with bid) ==========
#define QTILE 128
#define NQT3 (TT/QTILE)     // 32 q-tiles per batch
#define NCHUNK 144          // sum_{qt=0}^{31} ceil((qt+1)/4)

__global__ __launch_bounds__(256,2) void k_attn13(
    const f16* __restrict__ qhb, const f16* __restrict__ khb,
    const f16* __restrict__ khT, f16* __restrict__ part)
{
  int bid = blockIdx.x;
  int b = bid / NCHUNK;
  int rem = bid - b*NCHUNK;
  int qt = 0, chunk = 0;
  // LPT: large qt (8-iter blocks) first
  #pragma unroll 1
  for (int j = NQT3-1; j >= 0; j--){
    int nch = (j + 4) >> 2;     // ceil((j+1)/4)
    if (rem < nch){ qt = j; chunk = rem; break; }
    rem -= nch;
  }
  int kt0 = chunk * 8;
  int kt1 = min(kt0 + 7, 2*qt + 1);
  int t0 = qt * QTILE;

  __shared__ __align__(16) f16 Kb[64*136];     // [key][dim],  stride 136 (17408 B)
  __shared__ __align__(16) f16 Kt[128*72];     // [dim][key],  stride 72  (18432 B)
  __shared__ __align__(16) f16 Ps[4][32*72];   // per-wave P fp16, [q][key], stride 72 (18432 B)

  int tid  = threadIdx.x;
  int w    = tid >> 6;
  int lane = tid & 63;
  int n16  = lane & 15;
  int g    = lane >> 4;

  const f16* qg  = qhb + (size_t)b*TT*DD;
  const f16* kg  = khb + (size_t)b*TT*DD;
  const f16* ktg = khT + (size_t)b*DD*TT;

  int sb_r  = tid >> 4, sb_c = (tid & 15)*8;   // Kb staging base
  int st_r  = tid >> 3, st_c = (tid & 7)*8;    // Kt staging base

  half8 qa[2][4];   // Q rows; used as MFMA B-operand (A/B lane maps identical for 16x16x32 f16)
  #pragma unroll
  for (int p = 0; p < 2; p++){
    const f16* qrow = qg + (size_t)(t0 + 32*w + 16*p + n16)*DD + g*8;
    #pragma unroll
    for (int c = 0; c < 4; c++) qa[p][c] = *(const half8*)(qrow + 32*c);
  }
  f32x4 acc[2][8];
  #pragma unroll
  for (int p = 0; p < 2; p++)
    #pragma unroll
    for (int i = 0; i < 8; i++) acc[p][i] = (f32x4){0.f,0.f,0.f,0.f};

  f16* psw = &Ps[w][0];

  // ---- register prefetch of first K tile ----
  half8 sKb[4], sKt[4];
  {
    int s0 = kt0 * 64;
    #pragma unroll
    for (int it = 0; it < 4; it++)
      sKb[it] = *(const half8*)(kg + (size_t)(s0 + sb_r + it*16)*DD + sb_c);
    #pragma unroll
    for (int it = 0; it < 4; it++)
      sKt[it] = *(const half8*)(ktg + (size_t)(st_r + it*32)*TT + s0 + st_c);
  }

  for (int kt = kt0; kt <= kt1; kt++){
    #pragma unroll
    for (int it = 0; it < 4; it++)
      *(half8*)(Kb + (sb_r + it*16)*136 + sb_c) = sKb[it];
    #pragma unroll
    for (int it = 0; it < 4; it++)
      *(half8*)(Kt + (st_r + it*32)*72 + st_c) = sKt[it];
    __syncthreads();

    if (kt < kt1){
      int s0n = (kt+1) * 64;
      #pragma unroll
      for (int it = 0; it < 4; it++)
        sKb[it] = *(const half8*)(kg + (size_t)(s0n + sb_r + it*16)*DD + sb_c);
      #pragma unroll
      for (int it = 0; it < 4; it++)
        sKt[it] = *(const half8*)(ktg + (size_t)(st_r + it*32)*TT + s0n + st_c);
    }

    int s0 = kt * 64;
    // ---- QK^T transposed: A = K rows (Kb), B = Q regs -> S^T[m=key][n=query] ----
    f32x4 s_acc[2][4];
    #pragma unroll
    for (int p = 0; p < 2; p++)
      #pragma unroll
      for (int n = 0; n < 4; n++) s_acc[p][n] = (f32x4){0.f,0.f,0.f,0.f};
    #pragma unroll
    for (int c = 0; c < 4; c++){
      #pragma unroll
      for (int n = 0; n < 4; n++){
        half8 af = *(const half8*)(Kb + (16*n + n16)*136 + 32*c + g*8);
        s_acc[0][n] = __builtin_amdgcn_mfma_f32_16x16x32_f16(af, qa[0][c], s_acc[0][n], 0,0,0);
        s_acc[1][n] = __builtin_amdgcn_mfma_f32_16x16x32_f16(af, qa[1][c], s_acc[1][n], 0,0,0);
      }
    }
    // ---- sin + mask; lane holds q=n16, keys 16n+4g+r -> pack 4 keys -> ONE b64 write ----
    #pragma unroll
    for (int p = 0; p < 2; p++){
      int qrow = t0 + 32*w + 16*p + n16;
      #pragma unroll
      for (int n = 0; n < 4; n++){
        int keyr = s0 + 16*n + 4*g;
        float v0 = (keyr     <= qrow) ? __sinf(s_acc[p][n][0]) : 0.f;
        float v1 = (keyr + 1 <= qrow) ? __sinf(s_acc[p][n][1]) : 0.f;
        float v2 = (keyr + 2 <= qrow) ? __sinf(s_acc[p][n][2]) : 0.f;
        float v3 = (keyr + 3 <= qrow) ? __sinf(s_acc[p][n][3]) : 0.f;
        i32x2 pw = { pack2(v0, v1), pack2(v2, v3) };
        *(i32x2*)(psw + (16*p + n16)*72 + 16*n + 4*g) = pw;
      }
    }
    // intra-wave RAW on psw ordered by lgkmcnt (per-wave buffer, no barrier)

    // ---- PV: A = P rows (Ps[q][key] b128), B = Kt rows -> O[q][dim] ----
    #pragma unroll
    for (int h = 0; h < 2; h++){
      half8 pa[2];
      #pragma unroll
      for (int p = 0; p < 2; p++)
        pa[p] = *(const half8*)(psw + (16*p + n16)*72 + 32*h + 8*g);
      #pragma unroll
      for (int nt = 0; nt < 8; nt++){
        half8 bf = *(const half8*)(Kt + (16*nt + n16)*72 + 32*h + 8*g);
        acc[0][nt] = __builtin_amdgcn_mfma_f32_16x16x32_f16(pa[0], bf, acc[0][nt], 0,0,0);
        acc[1][nt] = __builtin_amdgcn_mfma_f32_16x16x32_f16(pa[1], bf, acc[1][nt], 0,0,0);
      }
    }
    __syncthreads();   // protect Kb/Kt/psw before next staging
  }

  // ---- epilogue: fp16 partial store ([q][dim] contiguous per chunk) ----
  f16* pb = part + (size_t)bid*(QTILE*DD) + (32*w)*DD;
  #pragma unroll
  for (int p = 0; p < 2; p++){
    #pragma unroll
    for (int nt = 0; nt < 8; nt++){
      #pragma unroll
      for (int r = 0; r < 4; r++){
        pb[(size_t)(16*p + 4*g + r)*DD + 16*nt + n16] = (f16)acc[p][nt][r];
      }
    }
  }
}

// ================= k_reduce: att = sum of fp16 partials (reversed-prefix base) ================
__global__ __launch_bounds__(256) void k_reduce(
    const f16* __restrict__ part, float* __restrict__ att)
{
  int bid = blockIdx.x;            // BB * 32 * 8 blocks
  int rg = bid & 7;
  int qt = (bid >> 3) & 31;
  int b  = bid >> 8;
  int nc = (qt + 4) >> 2;          // chunks for this q-tile
  int base = 0;                    // LPT order: chunks for qt sit after all larger qt's chunks
  #pragma unroll 1
  for (int j = NQT3-1; j > qt; j--) base += (j + 4) >> 2;
  int tid = threadIdx.x;
  size_t off = (size_t)rg*(16*DD) + tid*8;
  const f16* src = part + ((size_t)b*NCHUNK + base)*(QTILE*DD) + off;
  float a[8];
  {
    half8 v = *(const half8*)(src);
    #pragma unroll
    for (int u = 0; u < 8; u++) a[u] = (float)v[u];
  }
  for (int c = 1; c < nc; c++){
    half8 v = *(const half8*)(src + (size_t)c*(QTILE*DD));
    #pragma unroll
    for (int u = 0; u < 8; u++) a[u] += (float)v[u];
  }
  float* dst = att + ((size_t)b*TT + (size_t)qt*QTILE)*DD + off;
  f32x4 o0 = {a[0],a[1],a[2],a[3]}, o1 = {a[4],a[5],a[6],a[7]};
  *(f32x4*)(dst) = o0;
  *(f32x4*)(dst + 4) = o1;
}

// ====== k_comb: ki = proj(mf + att@Wo + bo); vsum += w*ki; retract (fp16 Wo in LDS) ===========
__global__ __launch_bounds__(256) void k_comb(
    const float* __restrict__ z, const float* __restrict__ Wo, const float* __restrict__ bo,
    const float* __restrict__ mf, const float* __restrict__ att,
    const float* __restrict__ zin, float* __restrict__ zout,
    float* __restrict__ vsum, float* __restrict__ out,
    float wsum, float cretr, int first, int last)
{
  __shared__ f16 Wh[DD*DD];      // 32 KB
  __shared__ float As[32*DD];    // 16 KB
  int tid = threadIdx.x;
  int r0 = blockIdx.x * 32;
  stage_w_f16(tid, Wo, Wh);
  #pragma unroll
  for (int it = 0; it < 4; it++){
    int idx = tid + it*256;
    *(f32x4*)(As + idx*4) = *(const f32x4*)(att + (size_t)r0*DD + idx*4);
  }
  __syncthreads();
  int c = tid & 15, rr = tid >> 4;
  float kur0[8], kur1[8];
  #pragma unroll
  for (int u = 0; u < 8; u++){ float bv = bo[c*8+u]; kur0[u] = bv; kur1[u] = bv; }
  const float* ar0 = As + rr*DD;
  const float* ar1 = As + (rr+16)*DD;
  #pragma unroll 4
  for (int i = 0; i < DD; i++){
    half8 wv = *(const half8*)(Wh + i*DD + c*8);
    float a0 = ar0[i], a1 = ar1[i];
    #pragma unroll
    for (int u = 0; u < 8; u++){
      float w = (float)wv[u];
      kur0[u] = fmaf(a0, w, kur0[u]);
      kur1[u] = fmaf(a1, w, kur1[u]);
    }
  }
  size_t o0 = (size_t)(r0+rr)*DD + c*8;
  size_t o1 = (size_t)(r0+rr+16)*DD + c*8;
  float tot0[8], tot1[8], zi0[8], zi1[8];
  {
    f32x4 m0a = *(const f32x4*)(mf + o0), m0b = *(const f32x4*)(mf + o0 + 4);
    f32x4 m1a = *(const f32x4*)(mf + o1), m1b = *(const f32x4*)(mf + o1 + 4);
    f32x4 z0a = *(const f32x4*)(zin + o0), z0b = *(const f32x4*)(zin + o0 + 4);
    f32x4 z1a = *(const f32x4*)(zin + o1), z1b = *(const f32x4*)(zin + o1 + 4);
    #pragma unroll
    for (int u = 0; u < 4; u++){
      tot0[u] = m0a[u] + kur0[u]; tot0[4+u] = m0b[u] + kur0[4+u];
      tot1[u] = m1a[u] + kur1[u]; tot1[4+u] = m1b[u] + kur1[4+u];
      zi0[u] = z0a[u]; zi0[4+u] = z0b[u];
      zi1[u] = z1a[u]; zi1[4+u] = z1b[u];
    }
  }
  float p0 = 0.f, p1 = 0.f;
  #pragma unroll
  for (int u = 0; u < 8; u++){ p0 = fmaf(tot0[u], zi0[u], p0); p1 = fmaf(tot1[u], zi1[u], p1); }
  #pragma unroll
  for (int m = 1; m < 16; m <<= 1){ p0 += __shfl_xor(p0, m, 16); p1 += __shfl_xor(p1, m, 16); }
  float ki0[8], ki1[8], vs0[8], vs1[8];
  #pragma unroll
  for (int u = 0; u < 8; u++){
    ki0[u] = tot0[u] - p0 * zi0[u];
    ki1[u] = tot1[u] - p1 * zi1[u];
  }
  if (first){
    #pragma unroll
    for (int u = 0; u < 8; u++){ vs0[u] = wsum*ki0[u]; vs1[u] = wsum*ki1[u]; }
  } else {
    f32x4 v0a = *(const f32x4*)(vsum + o0), v0b = *(const f32x4*)(vsum + o0 + 4);
    f32x4 v1a = *(const f32x4*)(vsum + o1), v1b = *(const f32x4*)(vsum + o1 + 4);
    #pragma unroll
    for (int u = 0; u < 4; u++){
      vs0[u] = fmaf(wsum, ki0[u], v0a[u]); vs0[4+u] = fmaf(wsum, ki0[4+u], v0b[u]);
      vs1[u] = fmaf(wsum, ki1[u], v1a[u]); vs1[4+u] = fmaf(wsum, ki1[4+u], v1b[u]);
    }
  }
  if (!last){
    f32x4 va = {vs0[0],vs0[1],vs0[2],vs0[3]}, vb = {vs0[4],vs0[5],vs0[6],vs0[7]};
    f32x4 vc = {vs1[0],vs1[1],vs1[2],vs1[3]}, vd = {vs1[4],vs1[5],vs1[6],vs1[7]};
    *(f32x4*)(vsum + o0) = va; *(f32x4*)(vsum + o0 + 4) = vb;
    *(f32x4*)(vsum + o1) = vc; *(f32x4*)(vsum + o1 + 4) = vd;
  }
  float nz0[8], nz1[8];
  {
    f32x4 z0a = *(const f32x4*)(z + o0), z0b = *(const f32x4*)(z + o0 + 4);
    f32x4 z1a = *(const f32x4*)(z + o1), z1b = *(const f32x4*)(z + o1 + 4);
    #pragma unroll
    for (int u = 0; u < 4; u++){
      float d0a = last ? vs0[u]*(1.f/6.f)   : cretr*ki0[u];
      float d0b = last ? vs0[4+u]*(1.f/6.f) : cretr*ki0[4+u];
      float d1a = last ? vs1[u]*(1.f/6.f)   : cretr*ki1[u];
      float d1b = last ? vs1[4+u]*(1.f/6.f) : cretr*ki1[4+u];
      nz0[u] = z0a[u] + d0a; nz0[4+u] = z0b[u] + d0b;
      nz1[u] = z1a[u] + d1a; nz1[4+u] = z1b[u] + d1b;
    }
  }
  float n0 = 0.f, n1 = 0.f;
  #pragma unroll
  for (int u = 0; u < 8; u++){ n0 = fmaf(nz0[u], nz0[u], n0); n1 = fmaf(nz1[u], nz1[u], n1); }
  #pragma unroll
  for (int m = 1; m < 16; m <<= 1){ n0 += __shfl_xor(n0, m, 16); n1 += __shfl_xor(n1, m, 16); }
  float i0 = 1.f / fmaxf(sqrtf(n0), 1e-8f);
  float i1 = 1.f / fmaxf(sqrtf(n1), 1e-8f);
  float* dst = last ? out : zout;
  f32x4 ra = {nz0[0]*i0, nz0[1]*i0, nz0[2]*i0, nz0[3]*i0};
  f32x4 rb = {nz0[4]*i0, nz0[5]*i0, nz0[6]*i0, nz0[7]*i0};
  f32x4 rc = {nz1[0]*i1, nz1[1]*i1, nz1[2]*i1, nz1[3]*i1};
  f32x4 rd = {nz1[4]*i1, nz1[5]*i1, nz1[6]*i1, nz1[7]*i1};
  *(f32x4*)(dst + o0) = ra; *(f32x4*)(dst + o0 + 4) = rb;
  *(f32x4*)(dst + o1) = rc; *(f32x4*)(dst + o1 + 4) = rd;
}

extern "C" void kernel_launch(void* const* d_in, const int* in_sizes, int n_in,
                              void* d_out, int out_size, void* d_ws, size_t ws_size,
                              hipStream_t stream) {
  const float* z  = (const float*)d_in[0];
  const float* ck = (const float*)d_in[1];
  const float* cb = (const float*)d_in[2];
  const float* Wq = (const float*)d_in[3];
  const float* bq = (const float*)d_in[4];
  const float* Wk = (const float*)d_in[5];
  const float* bk = (const float*)d_in[6];
  const float* Wo = (const float*)d_in[7];
  const float* bo = (const float*)d_in[8];
  float* out = (float*)d_out;

  float* mf   = (float*)d_ws;          // [B,T,D] f32
  float* zc   = mf   + NELT;
  float* att  = zc   + NELT;
  float* vsum = att  + NELT;
  f16*   khb  = (f16*)(vsum + NELT);   // fp16 [B,T,D]
  f16*   khT  = khb  + NELT;           // fp16 [B,D,T]
  f16*   qhb  = khT  + NELT;           // fp16 [B,T,D]
  f16*   part = qhb  + NELT;           // [BB*NCHUNK][128][128] fp16 partials (~9.4 MB)

  k_prep<<<1024, 256, 0, stream>>>(z, Wk, bk, ck, cb, Wq, bq, khb, khT, qhb, mf);

  const float wv[4] = {1.f, 2.f, 2.f, 1.f};
  const float cv[4] = {0.5f, 0.5f, 1.f, 0.f};
  for (int st = 0; st < 4; st++){
    const float* zcur = (st == 0) ? z : zc;
    if (st > 0)
      k_q   <<<NROW/32, 256, 0, stream>>>(zcur, Wq, bq, qhb);
    k_attn13<<<BB*NCHUNK, 256, 0, stream>>>(qhb, khb, khT, part);
    k_reduce<<<BB*NQT3*8, 256, 0, stream>>>(part, att);
    k_comb  <<<NROW/32, 256, 0, stream>>>(z, Wo, bo, mf, att, zcur, zc, vsum, out,
                                          wv[st], cv[st], st == 0, st == 3);
  }
}

// Round 21
// 289.864 us; speedup vs baseline: 1.1362x; 1.0090x over previous
//
#include <hip/hip_runtime.h>
#include <hip/hip_bf16.h>

#define BB 2
#define TT 4096
#define DD 128
#define KK 256
#define NROW (BB*TT)    // 8192 rows
#define NELT (NROW*DD)  // 1048576 elements per [B,T,D] buffer

typedef _Float16 f16;
typedef __attribute__((ext_vector_type(8))) f16 half8;
typedef __attribute__((ext_vector_type(2))) __fp16 fp16x2;
typedef __attribute__((ext_vector_type(4))) float f32x4;
typedef __attribute__((ext_vector_type(2))) int i32x2;

__device__ __forceinline__ int pack2(float a, float b){
  fp16x2 h = __builtin_amdgcn_cvt_pkrtz(a, b);
  return __builtin_bit_cast(int, h);
}

// ---- stage a 128x128 f32 weight matrix into LDS as fp16 (32 KB) ----
__device__ __forceinline__ void stage_w_f16(int tid, const float* __restrict__ W, f16* Wh){
  #pragma unroll
  for (int it = 0; it < 8; it++){
    int idx = tid + it*256;               // 2048 half8 chunks
    f32x4 a = *(const f32x4*)(W + (size_t)idx*8);
    f32x4 b = *(const f32x4*)(W + (size_t)idx*8 + 4);
    half8 h;
    #pragma unroll
    for (int u = 0; u < 4; u++){ h[u] = (f16)a[u]; h[4+u] = (f16)b[u]; }
    *(half8*)(Wh + (size_t)idx*8) = h;
  }
}

// ---- shared helper: 32-row fp32 matvec (fp16 W in LDS) + normalize -> fp16 rows (+transpose)
__device__ __forceinline__ void proj_norm_rows(
    int tid, int r0,
    const float* __restrict__ src, const float* __restrict__ W, const float* __restrict__ bias,
    f16* __restrict__ dst, f16* __restrict__ dstT)
{
  __shared__ f16 Wh[DD*DD];      // 32 KB
  __shared__ float zs[32*DD];    // 16 KB
  stage_w_f16(tid, W, Wh);
  #pragma unroll
  for (int it = 0; it < 4; it++){
    int idx = tid + it*256;
    *(f32x4*)(zs + idx*4) = *(const f32x4*)(src + (size_t)r0*DD + idx*4);
  }
  __syncthreads();
  int c = tid & 15, rr = tid >> 4;
  float acc0[8], acc1[8];
  #pragma unroll
  for (int u = 0; u < 8; u++){ float bv = bias[c*8+u]; acc0[u] = bv; acc1[u] = bv; }
  const float* zr0 = zs + rr*DD;
  const float* zr1 = zs + (rr+16)*DD;
  #pragma unroll 4
  for (int i = 0; i < DD; i++){
    half8 wv = *(const half8*)(Wh + i*DD + c*8);
    float a0 = zr0[i], a1 = zr1[i];
    #pragma unroll
    for (int u = 0; u < 8; u++){
      float w = (float)wv[u];
      acc0[u] = fmaf(a0, w, acc0[u]);
      acc1[u] = fmaf(a1, w, acc1[u]);
    }
  }
  float s0 = 0.f, s1 = 0.f;
  #pragma unroll
  for (int u = 0; u < 8; u++){ s0 = fmaf(acc0[u], acc0[u], s0); s1 = fmaf(acc1[u], acc1[u], s1); }
  #pragma unroll
  for (int m = 1; m < 16; m <<= 1){ s0 += __shfl_xor(s0, m, 16); s1 += __shfl_xor(s1, m, 16); }
  float inv0 = 1.f / fmaxf(sqrtf(s0), 1e-8f);
  float inv1 = 1.f / fmaxf(sqrtf(s1), 1e-8f);
  half8 h0, h1;
  #pragma unroll
  for (int u = 0; u < 8; u++){ h0[u] = (f16)(acc0[u]*inv0); h1[u] = (f16)(acc1[u]*inv1); }
  int row0 = r0 + rr, row1 = row0 + 16;
  *(half8*)(dst + (size_t)row0*DD + c*8) = h0;
  *(half8*)(dst + (size_t)row1*DD + c*8) = h1;
  if (dstT){
    int b = row0 >> 12, t0 = row0 & 4095, t1 = row1 & 4095;
    #pragma unroll
    for (int u = 0; u < 8; u++){
      dstT[((size_t)b*DD + c*8 + u)*TT + t0] = h0[u];
      dstT[((size_t)b*DD + c*8 + u)*TT + t1] = h1[u];
    }
  }
}

// ======== k_prep: merged one-shot. blocks 0..511: conv; 512..767: k-proj; 768..1023: q0-proj ==
__global__ __launch_bounds__(256) void k_prep(
    const float* __restrict__ z, const float* __restrict__ Wk, const float* __restrict__ bk,
    const float* __restrict__ ck, const float* __restrict__ cb,
    const float* __restrict__ Wq, const float* __restrict__ bq,
    f16* __restrict__ khb, f16* __restrict__ khT, f16* __restrict__ qhb,
    float* __restrict__ mf)
{
  int tid = threadIdx.x;
  if (blockIdx.x < 512){
    // ---- conv: register sliding window (heaviest; launched first for LPT) ----
    int bid = blockIdx.x;
    int d = tid & 127, tg = tid >> 7;
    int b = bid >> 8;
    int tbase = ((bid & 255) << 4) + tg*8;
    const float* zb = z + (size_t)b*TT*DD;
    float acc[8];
    #pragma unroll
    for (int j = 0; j < 8; j++) acc[j] = 0.f;
    float ckq[8];
    #pragma unroll
    for (int u = 0; u < 8; u++) ckq[u] = 0.f;
    int sstart = tbase - (KK-1);
    for (int ch = 0; ch < 33; ch++){
      #pragma unroll
      for (int u = 0; u < 8; u++){
        int base = ch*8 + u;
        int s = sstart + base;
        float zv = ((unsigned)s < (unsigned)TT && base < 263) ? zb[(size_t)s*DD + d] : 0.f;
        ckq[u] = (base < KK) ? ck[(size_t)base*DD + d] : 0.f;
        #pragma unroll
        for (int j = 0; j < 8; j++) acc[j] = fmaf(ckq[(u-j)&7], zv, acc[j]);
      }
    }
    float cbv = cb[d];
    #pragma unroll
    for (int j = 0; j < 8; j++)
      mf[((size_t)b*TT + tbase + j)*DD + d] = acc[j] + cbv;
  } else if (blockIdx.x < 768){
    proj_norm_rows(tid, (blockIdx.x - 512) * 32, z, Wk, bk, khb, khT);
  } else {
    proj_norm_rows(tid, (blockIdx.x - 768) * 32, z, Wq, bq, qhb, nullptr);
  }
}

// ================= k_q: q_hat = normalize(zcur@Wq+bq) -> fp16 (stages 1..3) =================
__global__ __launch_bounds__(256) void k_q(
    const float* __restrict__ zcur, const float* __restrict__ Wq, const float* __restrict__ bq,
    f16* __restrict__ qhb)
{
  proj_norm_rows(threadIdx.x, blockIdx.x * 32, zcur, Wq, bq, qhb, nullptr);
}

// ====== MFMA attention v13: chunks of 8 key-tiles, LPT order (qt descending with bid) ==========
#define QTILE 128
#define NQT3 (TT/QTILE)     // 32 q-tiles per batch
#define NCHUNK 144          // sum_{qt=0}^{31} ceil((qt+1)/4)

__global__ __launch_bounds__(256,2) void k_attn13(
    const f16* __restrict__ qhb, const f16* __restrict__ khb,
    const f16* __restrict__ khT, f16* __restrict__ part)
{
  int bid = blockIdx.x;
  int b = bid / NCHUNK;
  int rem = bid - b*NCHUNK;
  int qt = 0, chunk = 0;
  // LPT: large qt (8-iter blocks) first
  #pragma unroll 1
  for (int j = NQT3-1; j >= 0; j--){
    int nch = (j + 4) >> 2;     // ceil((j+1)/4)
    if (rem < nch){ qt = j; chunk = rem; break; }
    rem -= nch;
  }
  int kt0 = chunk * 8;
  int kt1 = min(kt0 + 7, 2*qt + 1);
  int t0 = qt * QTILE;

  __shared__ __align__(16) f16 Kb[64*136];     // [key][dim],  stride 136 (17408 B)
  __shared__ __align__(16) f16 Kt[128*72];     // [dim][key],  stride 72  (18432 B)
  __shared__ __align__(16) f16 Ps[4][32*72];   // per-wave P fp16, [q][key], stride 72 (18432 B)

  int tid  = threadIdx.x;
  int w    = tid >> 6;
  int lane = tid & 63;
  int n16  = lane & 15;
  int g    = lane >> 4;

  const f16* qg  = qhb + (size_t)b*TT*DD;
  const f16* kg  = khb + (size_t)b*TT*DD;
  const f16* ktg = khT + (size_t)b*DD*TT;

  int sb_r  = tid >> 4, sb_c = (tid & 15)*8;   // Kb staging base
  int st_r  = tid >> 3, st_c = (tid & 7)*8;    // Kt staging base

  half8 qa[2][4];   // Q rows; used as MFMA B-operand (A/B lane maps identical for 16x16x32 f16)
  #pragma unroll
  for (int p = 0; p < 2; p++){
    const f16* qrow = qg + (size_t)(t0 + 32*w + 16*p + n16)*DD + g*8;
    #pragma unroll
    for (int c = 0; c < 4; c++) qa[p][c] = *(const half8*)(qrow + 32*c);
  }
  f32x4 acc[2][8];
  #pragma unroll
  for (int p = 0; p < 2; p++)
    #pragma unroll
    for (int i = 0; i < 8; i++) acc[p][i] = (f32x4){0.f,0.f,0.f,0.f};

  f16* psw = &Ps[w][0];

  // ---- register prefetch of first K tile ----
  half8 sKb[4], sKt[4];
  {
    int s0 = kt0 * 64;
    #pragma unroll
    for (int it = 0; it < 4; it++)
      sKb[it] = *(const half8*)(kg + (size_t)(s0 + sb_r + it*16)*DD + sb_c);
    #pragma unroll
    for (int it = 0; it < 4; it++)
      sKt[it] = *(const half8*)(ktg + (size_t)(st_r + it*32)*TT + s0 + st_c);
  }

  for (int kt = kt0; kt <= kt1; kt++){
    #pragma unroll
    for (int it = 0; it < 4; it++)
      *(half8*)(Kb + (sb_r + it*16)*136 + sb_c) = sKb[it];
    #pragma unroll
    for (int it = 0; it < 4; it++)
      *(half8*)(Kt + (st_r + it*32)*72 + st_c) = sKt[it];
    __syncthreads();

    if (kt < kt1){
      int s0n = (kt+1) * 64;
      #pragma unroll
      for (int it = 0; it < 4; it++)
        sKb[it] = *(const half8*)(kg + (size_t)(s0n + sb_r + it*16)*DD + sb_c);
      #pragma unroll
      for (int it = 0; it < 4; it++)
        sKt[it] = *(const half8*)(ktg + (size_t)(st_r + it*32)*TT + s0n + st_c);
    }

    int s0 = kt * 64;
    // ---- QK^T transposed: A = K rows (Kb), B = Q regs -> S^T[m=key][n=query] ----
    f32x4 s_acc[2][4];
    #pragma unroll
    for (int p = 0; p < 2; p++)
      #pragma unroll
      for (int n = 0; n < 4; n++) s_acc[p][n] = (f32x4){0.f,0.f,0.f,0.f};
    #pragma unroll
    for (int c = 0; c < 4; c++){
      #pragma unroll
      for (int n = 0; n < 4; n++){
        half8 af = *(const half8*)(Kb + (16*n + n16)*136 + 32*c + g*8);
        s_acc[0][n] = __builtin_amdgcn_mfma_f32_16x16x32_f16(af, qa[0][c], s_acc[0][n], 0,0,0);
        s_acc[1][n] = __builtin_amdgcn_mfma_f32_16x16x32_f16(af, qa[1][c], s_acc[1][n], 0,0,0);
      }
    }
    // ---- sin + mask; lane holds q=n16, keys 16n+4g+r -> pack 4 keys -> ONE b64 write ----
    #pragma unroll
    for (int p = 0; p < 2; p++){
      int qrow = t0 + 32*w + 16*p + n16;
      #pragma unroll
      for (int n = 0; n < 4; n++){
        int keyr = s0 + 16*n + 4*g;
        float v0 = (keyr     <= qrow) ? __sinf(s_acc[p][n][0]) : 0.f;
        float v1 = (keyr + 1 <= qrow) ? __sinf(s_acc[p][n][1]) : 0.f;
        float v2 = (keyr + 2 <= qrow) ? __sinf(s_acc[p][n][2]) : 0.f;
        float v3 = (keyr + 3 <= qrow) ? __sinf(s_acc[p][n][3]) : 0.f;
        i32x2 pw = { pack2(v0, v1), pack2(v2, v3) };
        *(i32x2*)(psw + (16*p + n16)*72 + 16*n + 4*g) = pw;
      }
    }
    // intra-wave RAW on psw ordered by lgkmcnt (per-wave buffer, no barrier)

    // ---- PV: A = P rows (Ps[q][key] b128), B = Kt rows -> O[q][dim] ----
    #pragma unroll
    for (int h = 0; h < 2; h++){
      half8 pa[2];
      #pragma unroll
      for (int p = 0; p < 2; p++)
        pa[p] = *(const half8*)(psw + (16*p + n16)*72 + 32*h + 8*g);
      #pragma unroll
      for (int nt = 0; nt < 8; nt++){
        half8 bf = *(const half8*)(Kt + (16*nt + n16)*72 + 32*h + 8*g);
        acc[0][nt] = __builtin_amdgcn_mfma_f32_16x16x32_f16(pa[0], bf, acc[0][nt], 0,0,0);
        acc[1][nt] = __builtin_amdgcn_mfma_f32_16x16x32_f16(pa[1], bf, acc[1][nt], 0,0,0);
      }
    }
    __syncthreads();   // protect Kb/Kt/psw before next staging
  }

  // ---- epilogue: fp16 partial store ([q][dim] contiguous per chunk) ----
  f16* pb = part + (size_t)bid*(QTILE*DD) + (32*w)*DD;
  #pragma unroll
  for (int p = 0; p < 2; p++){
    #pragma unroll
    for (int nt = 0; nt < 8; nt++){
      #pragma unroll
      for (int r = 0; r < 4; r++){
        pb[(size_t)(16*p + 4*g + r)*DD + 16*nt + n16] = (f16)acc[p][nt][r];
      }
    }
  }
}

// ====== k_comb: inline fp16 split-K reduce (nc<=8, LPT base); ki = proj(mf + att@Wo + bo);
//        vsum += w*ki; retract (fp16 Wo in LDS) ======
__global__ __launch_bounds__(256) void k_comb(
    const float* __restrict__ z, const float* __restrict__ Wo, const float* __restrict__ bo,
    const float* __restrict__ mf, const f16* __restrict__ part,
    const float* __restrict__ zin, float* __restrict__ zout,
    float* __restrict__ vsum, float* __restrict__ out,
    float wsum, float cretr, int first, int last)
{
  __shared__ f16 Wh[DD*DD];      // 32 KB
  __shared__ float As[32*DD];    // 16 KB
  int tid = threadIdx.x;
  int r0 = blockIdx.x * 32;
  stage_w_f16(tid, Wo, Wh);
  // ---- inline split-K reduction of fp16 partials into As (rows r0..r0+31) ----
  {
    int b = r0 >> 12;
    int t = r0 & 4095;
    int qt = t >> 7;
    int ro = t & 127;
    int nc = (qt + 4) >> 2;
    int base = 0;                 // LPT reversed prefix: larger qt's chunks come first
    #pragma unroll 1
    for (int j = NQT3-1; j > qt; j--) base += (j + 4) >> 2;
    size_t sb = ((size_t)b*NCHUNK + base)*(QTILE*DD) + (size_t)ro*DD;
    #pragma unroll
    for (int it = 0; it < 2; it++){
      int idx = tid + it*256;     // 512 half8 slots = 4096 elements (32 rows x 128 dims)
      const f16* s = part + sb + (size_t)idx*8;
      float a[8];
      {
        half8 v = *(const half8*)(s);
        #pragma unroll
        for (int u = 0; u < 8; u++) a[u] = (float)v[u];
      }
      for (int cc = 1; cc < nc; cc++){
        half8 v = *(const half8*)(s + (size_t)cc*(QTILE*DD));
        #pragma unroll
        for (int u = 0; u < 8; u++) a[u] += (float)v[u];
      }
      f32x4 o0v = {a[0],a[1],a[2],a[3]}, o1v = {a[4],a[5],a[6],a[7]};
      *(f32x4*)(As + idx*8) = o0v;
      *(f32x4*)(As + idx*8 + 4) = o1v;
    }
  }
  __syncthreads();
  int c = tid & 15, rr = tid >> 4;
  float kur0[8], kur1[8];
  #pragma unroll
  for (int u = 0; u < 8; u++){ float bv = bo[c*8+u]; kur0[u] = bv; kur1[u] = bv; }
  const float* ar0 = As + rr*DD;
  const float* ar1 = As + (rr+16)*DD;
  #pragma unroll 4
  for (int i = 0; i < DD; i++){
    half8 wv = *(const half8*)(Wh + i*DD + c*8);
    float a0 = ar0[i], a1 = ar1[i];
    #pragma unroll
    for (int u = 0; u < 8; u++){
      float w = (float)wv[u];
      kur0[u] = fmaf(a0, w, kur0[u]);
      kur1[u] = fmaf(a1, w, kur1[u]);
    }
  }
  size_t o0 = (size_t)(r0+rr)*DD + c*8;
  size_t o1 = (size_t)(r0+rr+16)*DD + c*8;
  float tot0[8], tot1[8], zi0[8], zi1[8];
  {
    f32x4 m0a = *(const f32x4*)(mf + o0), m0b = *(const f32x4*)(mf + o0 + 4);
    f32x4 m1a = *(const f32x4*)(mf + o1), m1b = *(const f32x4*)(mf + o1 + 4);
    f32x4 z0a = *(const f32x4*)(zin + o0), z0b = *(const f32x4*)(zin + o0 + 4);
    f32x4 z1a = *(const f32x4*)(zin + o1), z1b = *(const f32x4*)(zin + o1 + 4);
    #pragma unroll
    for (int u = 0; u < 4; u++){
      tot0[u] = m0a[u] + kur0[u]; tot0[4+u] = m0b[u] + kur0[4+u];
      tot1[u] = m1a[u] + kur1[u]; tot1[4+u] = m1b[u] + kur1[4+u];
      zi0[u] = z0a[u]; zi0[4+u] = z0b[u];
      zi1[u] = z1a[u]; zi1[4+u] = z1b[u];
    }
  }
  float p0 = 0.f, p1 = 0.f;
  #pragma unroll
  for (int u = 0; u < 8; u++){ p0 = fmaf(tot0[u], zi0[u], p0); p1 = fmaf(tot1[u], zi1[u], p1); }
  #pragma unroll
  for (int m = 1; m < 16; m <<= 1){ p0 += __shfl_xor(p0, m, 16); p1 += __shfl_xor(p1, m, 16); }
  float ki0[8], ki1[8], vs0[8], vs1[8];
  #pragma unroll
  for (int u = 0; u < 8; u++){
    ki0[u] = tot0[u] - p0 * zi0[u];
    ki1[u] = tot1[u] - p1 * zi1[u];
  }
  if (first){
    #pragma unroll
    for (int u = 0; u < 8; u++){ vs0[u] = wsum*ki0[u]; vs1[u] = wsum*ki1[u]; }
  } else {
    f32x4 v0a = *(const f32x4*)(vsum + o0), v0b = *(const f32x4*)(vsum + o0 + 4);
    f32x4 v1a = *(const f32x4*)(vsum + o1), v1b = *(const f32x4*)(vsum + o1 + 4);
    #pragma unroll
    for (int u = 0; u < 4; u++){
      vs0[u] = fmaf(wsum, ki0[u], v0a[u]); vs0[4+u] = fmaf(wsum, ki0[4+u], v0b[u]);
      vs1[u] = fmaf(wsum, ki1[u], v1a[u]); vs1[4+u] = fmaf(wsum, ki1[4+u], v1b[u]);
    }
  }
  if (!last){
    f32x4 va = {vs0[0],vs0[1],vs0[2],vs0[3]}, vb = {vs0[4],vs0[5],vs0[6],vs0[7]};
    f32x4 vc = {vs1[0],vs1[1],vs1[2],vs1[3]}, vd = {vs1[4],vs1[5],vs1[6],vs1[7]};
    *(f32x4*)(vsum + o0) = va; *(f32x4*)(vsum + o0 + 4) = vb;
    *(f32x4*)(vsum + o1) = vc; *(f32x4*)(vsum + o1 + 4) = vd;
  }
  float nz0[8], nz1[8];
  {
    f32x4 z0a = *(const f32x4*)(z + o0), z0b = *(const f32x4*)(z + o0 + 4);
    f32x4 z1a = *(const f32x4*)(z + o1), z1b = *(const f32x4*)(z + o1 + 4);
    #pragma unroll
    for (int u = 0; u < 4; u++){
      float d0a = last ? vs0[u]*(1.f/6.f)   : cretr*ki0[u];
      float d0b = last ? vs0[4+u]*(1.f/6.f) : cretr*ki0[4+u];
      float d1a = last ? vs1[u]*(1.f/6.f)   : cretr*ki1[u];
      float d1b = last ? vs1[4+u]*(1.f/6.f) : cretr*ki1[4+u];
      nz0[u] = z0a[u] + d0a; nz0[4+u] = z0b[u] + d0b;
      nz1[u] = z1a[u] + d1a; nz1[4+u] = z1b[u] + d1b;
    }
  }
  float n0 = 0.f, n1 = 0.f;
  #pragma unroll
  for (int u = 0; u < 8; u++){ n0 = fmaf(nz0[u], nz0[u], n0); n1 = fmaf(nz1[u], nz1[u], n1); }
  #pragma unroll
  for (int m = 1; m < 16; m <<= 1){ n0 += __shfl_xor(n0, m, 16); n1 += __shfl_xor(n1, m, 16); }
  float i0 = 1.f / fmaxf(sqrtf(n0), 1e-8f);
  float i1 = 1.f / fmaxf(sqrtf(n1), 1e-8f);
  float* dst = last ? out : zout;
  f32x4 ra = {nz0[0]*i0, nz0[1]*i0, nz0[2]*i0, nz0[3]*i0};
  f32x4 rb = {nz0[4]*i0, nz0[5]*i0, nz0[6]*i0, nz0[7]*i0};
  f32x4 rc = {nz1[0]*i1, nz1[1]*i1, nz1[2]*i1, nz1[3]*i1};
  f32x4 rd = {nz1[4]*i1, nz1[5]*i1, nz1[6]*i1, nz1[7]*i1};
  *(f32x4*)(dst + o0) = ra; *(f32x4*)(dst + o0 + 4) = rb;
  *(f32x4*)(dst + o1) = rc; *(f32x4*)(dst + o1 + 4) = rd;
}

extern "C" void kernel_launch(void* const* d_in, const int* in_sizes, int n_in,
                              void* d_out, int out_size, void* d_ws, size_t ws_size,
                              hipStream_t stream) {
  const float* z  = (const float*)d_in[0];
  const float* ck = (const float*)d_in[1];
  const float* cb = (const float*)d_in[2];
  const float* Wq = (const float*)d_in[3];
  const float* bq = (const float*)d_in[4];
  const float* Wk = (const float*)d_in[5];
  const float* bk = (const float*)d_in[6];
  const float* Wo = (const float*)d_in[7];
  const float* bo = (const float*)d_in[8];
  float* out = (float*)d_out;

  float* mf   = (float*)d_ws;          // [B,T,D] f32
  float* zc   = mf   + NELT;
  float* vsum = zc   + NELT;
  f16*   khb  = (f16*)(vsum + NELT);   // fp16 [B,T,D]
  f16*   khT  = khb  + NELT;           // fp16 [B,D,T]
  f16*   qhb  = khT  + NELT;           // fp16 [B,T,D]
  f16*   part = qhb  + NELT;           // [BB*NCHUNK][128][128] fp16 partials (~9.4 MB)

  k_prep<<<1024, 256, 0, stream>>>(z, Wk, bk, ck, cb, Wq, bq, khb, khT, qhb, mf);

  const float wv[4] = {1.f, 2.f, 2.f, 1.f};
  const float cv[4] = {0.5f, 0.5f, 1.f, 0.f};
  for (int st = 0; st < 4; st++){
    const float* zcur = (st == 0) ? z : zc;
    if (st > 0)
      k_q   <<<NROW/32, 256, 0, stream>>>(zcur, Wq, bq, qhb);
    k_attn13<<<BB*NCHUNK, 256, 0, stream>>>(qhb, khb, khT, part);
    k_comb  <<<NROW/32, 256, 0, stream>>>(z, Wo, bo, mf, part, zcur, zc, vsum, out,
                                          wv[st], cv[st], st == 0, st == 3);
  }
}